// Round 2
// baseline (1657.749 us; speedup 1.0000x reference)
//
#include <hip/hip_runtime.h>

typedef unsigned int u32;

__device__ inline float sigmoidf_(float x) { return 1.f / (1.f + __expf(-x)); }

// ---------------------------------------------------------------------------
// Precompute pr = emb @ gcn_w[:, :128].T, pe = emb @ gcn_w[:,128:].T (fp32),
// and score tables srel = pr . attn_w, sent = pe . attn_w.
// Block: 256 threads = (which in {rel,ent}) x (d in 0..127). Weight row in regs,
// emb row via uniform (scalar) loads.
__global__ __launch_bounds__(256) void k_precompute(
    const float* __restrict__ emb, const float* __restrict__ gcn_w,
    const float* __restrict__ attn_w,
    float* __restrict__ pr, float* __restrict__ pe,
    float* __restrict__ srel, float* __restrict__ sent)
{
  const int t = threadIdx.x;
  const int which = t >> 7;   // 0: rel half (W cols 0..127), 1: ent half
  const int d = t & 127;
  float wv[128];
  {
    const float4* wrow = (const float4*)(gcn_w + d * 256 + which * 128);
    #pragma unroll
    for (int j = 0; j < 32; ++j) {
      float4 v = wrow[j];
      wv[4*j+0] = v.x; wv[4*j+1] = v.y; wv[4*j+2] = v.z; wv[4*j+3] = v.w;
    }
  }
  const float aw = attn_w[d];
  __shared__ float red[4];
  float* outt = which ? pe : pr;
  float* souts = which ? sent : srel;
  for (int i = blockIdx.x; i < 100001; i += gridDim.x) {
    const float* er = emb + (size_t)i * 128;
    float a0 = 0.f, a1 = 0.f, a2 = 0.f, a3 = 0.f;
    #pragma unroll
    for (int k = 0; k < 128; k += 4) {
      a0 += er[k + 0] * wv[k + 0];
      a1 += er[k + 1] * wv[k + 1];
      a2 += er[k + 2] * wv[k + 2];
      a3 += er[k + 3] * wv[k + 3];
    }
    float v = (a0 + a1) + (a2 + a3);
    outt[(size_t)i * 128 + d] = v;
    float pp = v * aw;
    #pragma unroll
    for (int off = 32; off; off >>= 1) pp += __shfl_down(pp, off, 64);
    __syncthreads();                       // previous-iter red reads done
    if ((t & 63) == 0) red[t >> 6] = pp;
    __syncthreads();
    if ((t & 127) == 0) souts[i] = red[(which << 1)] + red[(which << 1) + 1];
  }
}

// ---------------------------------------------------------------------------
// fp32 weight prep: Wih = w_ih; Wc = w_ih + w_hh[:, :256]; Wh1 = w_hh[:, :256];
// bsum = b_ih + b_hh
__global__ __launch_bounds__(256) void k_weights(
    const float* __restrict__ w_ih, const float* __restrict__ w_hh,
    const float* __restrict__ b_ih, const float* __restrict__ b_hh,
    float* __restrict__ Wih, float* __restrict__ Wc, float* __restrict__ Wh1,
    float* __restrict__ bsum)
{
  int idx = blockIdx.x * 256 + threadIdx.x;  // 0 .. 2048*256-1
  int j = idx >> 8, k = idx & 255;
  float wi = w_ih[idx];
  float wh = w_hh[j * 512 + k];
  Wih[idx] = wi; Wc[idx] = wi + wh; Wh1[idx] = wh;
  if (idx < 2048) bsum[idx] = b_ih[idx] + b_hh[idx];
}

// ---------------------------------------------------------------------------
// Neighbor pair encoder: out[n][coloff + d] = gw0*tanh(bias+accA) + gw1*tanh(bias+accB)
// One block (128 threads = 2 waves) per row n. Wave0 does hopA softmax, wave1 hopB.
__global__ __launch_bounds__(128) void k_neighbor(
    const int* __restrict__ connA, const int* __restrict__ connB,
    const float* __restrict__ pr, const float* __restrict__ pe,
    const float* __restrict__ srel, const float* __restrict__ sent,
    const float* __restrict__ gcn_wb, const float* __restrict__ gcn_b,
    const float* __restrict__ hop_gate,
    float* __restrict__ out, int coloff)
{
  const int n = blockIdx.x, t = threadIdx.x;
  __shared__ int idxA[64][2], idxB[64][2];
  __shared__ float wA[64], wB[64];
  {
    const int hop = t >> 6, nn = t & 63;
    const int* conn = hop ? connB : connA;
    int rel = conn[(n * 64 + nn) * 2 + 0];
    int ent = conn[(n * 64 + nn) * 2 + 1];
    int (*idx)[2] = hop ? idxB : idxA;
    idx[nn][0] = rel; idx[nn][1] = ent;
    float sc = srel[rel] + sent[ent];
    float m = sc;
    #pragma unroll
    for (int off = 32; off; off >>= 1) m = fmaxf(m, __shfl_xor(m, off, 64));
    float e = __expf(sc - m);
    float s = e;
    #pragma unroll
    for (int off = 32; off; off >>= 1) s += __shfl_xor(s, off, 64);
    (hop ? wB : wA)[nn] = e / s;
  }
  __syncthreads();
  const int d = t;                          // 0..127
  float accA = 0.f, accB = 0.f;
  #pragma unroll 4
  for (int k = 0; k < 64; ++k) {
    accA += wA[k] * (pr[(size_t)idxA[k][0] * 128 + d] + pe[(size_t)idxA[k][1] * 128 + d]);
    accB += wB[k] * (pr[(size_t)idxB[k][0] * 128 + d] + pe[(size_t)idxB[k][1] * 128 + d]);
  }
  float bias = gcn_wb[d] + gcn_b[d];
  float g0 = hop_gate[0], g1 = hop_gate[1];
  float mx = fmaxf(g0, g1);
  float e0 = __expf(g0 - mx), e1 = __expf(g1 - mx);
  float inv = 1.f / (e0 + e1);
  out[n * 256 + coloff + d] = e0 * inv * tanhf(bias + accA) + e1 * inv * tanhf(bias + accB);
}

// ---------------------------------------------------------------------------
// Support encoder: [5][256] -> support_g [5][256], support_m [256]. One block.
__global__ __launch_bounds__(256) void k_support(
    const float* __restrict__ sn,
    const float* __restrict__ p1_w, const float* __restrict__ p1_b,
    const float* __restrict__ p2_w, const float* __restrict__ p2_b,
    const float* __restrict__ ln_g, const float* __restrict__ ln_b,
    float* __restrict__ sg, float* __restrict__ sm)
{
  __shared__ float xs[5][256];
  __shared__ float h1[5][512];
  __shared__ float zz[5][256];
  __shared__ float r1[4], r2[4];
  const int t = threadIdx.x, lane = t & 63, wave = t >> 6;
  for (int i = t; i < 5 * 256; i += 256) xs[i >> 8][i & 255] = sn[i];
  __syncthreads();
  for (int o = wave; o < 5 * 512; o += 4) {       // h1 = relu(x@p1_w.T + p1_b)
    int r = o >> 9, j = o & 511;
    const float* wr = p1_w + j * 256;
    float acc = 0.f;
    #pragma unroll
    for (int q = 0; q < 4; ++q) acc += xs[r][lane + 64*q] * wr[lane + 64*q];
    #pragma unroll
    for (int off = 32; off; off >>= 1) acc += __shfl_xor(acc, off, 64);
    if (lane == 0) h1[r][j] = fmaxf(acc + p1_b[j], 0.f);
  }
  __syncthreads();
  for (int o = wave; o < 5 * 256; o += 4) {       // z = h1@p2_w.T + p2_b + x
    int r = o >> 8, j = o & 255;
    const float* wr = p2_w + j * 512;
    float acc = 0.f;
    #pragma unroll
    for (int q = 0; q < 8; ++q) acc += h1[r][lane + 64*q] * wr[lane + 64*q];
    #pragma unroll
    for (int off = 32; off; off >>= 1) acc += __shfl_xor(acc, off, 64);
    if (lane == 0) zz[r][j] = acc + p2_b[j] + xs[r][j];
  }
  __syncthreads();
  float smacc = 0.f;
  for (int r = 0; r < 5; ++r) {                   // LayerNorm per row
    float v = zz[r][t];
    float s1 = v, s2 = v * v;
    #pragma unroll
    for (int off = 32; off; off >>= 1) { s1 += __shfl_xor(s1, off, 64); s2 += __shfl_xor(s2, off, 64); }
    if (lane == 0) { r1[wave] = s1; r2[wave] = s2; }
    __syncthreads();
    float S1 = r1[0]+r1[1]+r1[2]+r1[3];
    float S2 = r2[0]+r2[1]+r2[2]+r2[3];
    __syncthreads();
    float mu = S1 * (1.f/256.f);
    float var = S2 * (1.f/256.f) - mu * mu;
    float g = (v - mu) * rsqrtf(var + 1e-6f) * ln_g[t] + ln_b[t];
    sg[r * 256 + t] = g;
    smacc += g;
  }
  sm[t] = smacc * 0.2f;
}

// ---------------------------------------------------------------------------
// SG2[r][j] = sum_k support_g[r][k] * w_hh[j][256+k]   ([5][2048])
__global__ __launch_bounds__(256) void k_sg2(
    const float* __restrict__ sg, const float* __restrict__ w_hh,
    float* __restrict__ SG2)
{
  __shared__ float s[5][256];
  const int t = threadIdx.x, lane = t & 63, wave = t >> 6;
  for (int i = t; i < 1280; i += 256) s[i >> 8][i & 255] = sg[i];
  __syncthreads();
  const int base = blockIdx.x * 256;
  for (int oi = wave; oi < 256; oi += 4) {
    int o = base + oi;                    // 0..10239 ; o = r*2048 + j
    int r = o >> 11, j = o & 2047;
    const float* wr = w_hh + j * 512 + 256;
    float acc = 0.f;
    #pragma unroll
    for (int q = 0; q < 4; ++q) acc += s[r][lane + 64*q] * wr[lane + 64*q];
    #pragma unroll
    for (int off = 32; off; off >>= 1) acc += __shfl_xor(acc, off, 64);
    if (lane == 0) SG2[o] = acc;
  }
}

// ---------------------------------------------------------------------------
// gates[B][2048] = X1@W1.T (+ X2@W2.T) (+ attn@SG2) + bsum
// 64x64 tile / block of 256 threads, thread = 4x4 outputs. fp32 VALU.
__global__ __launch_bounds__(256) void k_gates(
    const float* __restrict__ X1, const float* __restrict__ W1,
    const float* __restrict__ X2, const float* __restrict__ W2,
    const float* __restrict__ attn, const float* __restrict__ SG2,
    const float* __restrict__ bsum, float* __restrict__ gates)
{
  const int t = threadIdx.x;
  const int tx = t & 15, ty = t >> 4;
  const int row0 = (blockIdx.x >> 5) << 6;
  const int col0 = (blockIdx.x & 31) << 6;
  __shared__ float xs[32][68];   // k-major, padded
  __shared__ float ws[32][68];
  float acc[4][4];
  #pragma unroll
  for (int i = 0; i < 4; ++i)
    #pragma unroll
    for (int j = 0; j < 4; ++j) acc[i][j] = 0.f;

  for (int phase = 0; phase < 2; ++phase) {
    const float* X = phase ? X2 : X1;
    const float* W = phase ? W2 : W1;
    if (!X) break;
    for (int k0 = 0; k0 < 256; k0 += 32) {
      __syncthreads();
      #pragma unroll
      for (int s_ = 0; s_ < 2; ++s_) {
        int f4 = t + s_ * 256;           // 0..511
        int row = f4 >> 3;               // tile row / tile col
        int kq = (f4 & 7) << 2;          // 0,4,..,28
        float4 v = *(const float4*)&X[(row0 + row) * 256 + k0 + kq];
        xs[kq+0][row] = v.x; xs[kq+1][row] = v.y; xs[kq+2][row] = v.z; xs[kq+3][row] = v.w;
        float4 u = *(const float4*)&W[(col0 + row) * 256 + k0 + kq];
        ws[kq+0][row] = u.x; ws[kq+1][row] = u.y; ws[kq+2][row] = u.z; ws[kq+3][row] = u.w;
      }
      __syncthreads();
      #pragma unroll
      for (int k = 0; k < 32; ++k) {
        float4 av = *(const float4*)&xs[k][ty << 2];
        float4 bv = *(const float4*)&ws[k][tx << 2];
        float a_[4] = {av.x, av.y, av.z, av.w};
        float b_[4] = {bv.x, bv.y, bv.z, bv.w};
        #pragma unroll
        for (int i = 0; i < 4; ++i)
          #pragma unroll
          for (int j = 0; j < 4; ++j) acc[i][j] += a_[i] * b_[j];
      }
    }
  }
  if (attn) {
    __shared__ float at[64][6];
    __shared__ float sg2t[5][64];
    __syncthreads();
    for (int i = t; i < 64 * 5; i += 256) at[i / 5][i % 5] = attn[(row0 + i / 5) * 8 + (i % 5)];
    for (int i = t; i < 5 * 64; i += 256) sg2t[i >> 6][i & 63] = SG2[(i >> 6) * 2048 + col0 + (i & 63)];
    __syncthreads();
    #pragma unroll
    for (int r = 0; r < 5; ++r) {
      float bj[4];
      #pragma unroll
      for (int j = 0; j < 4; ++j) bj[j] = sg2t[r][(tx << 2) + j];
      #pragma unroll
      for (int i = 0; i < 4; ++i) {
        float a = at[(ty << 2) + i][r];
        #pragma unroll
        for (int j = 0; j < 4; ++j) acc[i][j] += a * bj[j];
      }
    }
  }
  #pragma unroll
  for (int i = 0; i < 4; ++i) {
    int row = row0 + (ty << 2) + i;
    int col = col0 + (tx << 2);
    float4 o;
    o.x = acc[i][0] + bsum[col + 0];
    o.y = acc[i][1] + bsum[col + 1];
    o.z = acc[i][2] + bsum[col + 2];
    o.w = acc[i][3] + bsum[col + 3];
    *(float4*)&gates[(size_t)row * 2048 + col] = o;
  }
}

// ---------------------------------------------------------------------------
__device__ inline float block_sum256(float v, float* red) {
  const int lane = threadIdx.x & 63, wave = threadIdx.x >> 6;
  #pragma unroll
  for (int off = 32; off; off >>= 1) v += __shfl_xor(v, off, 64);
  if (lane == 0) red[wave] = v;
  __syncthreads();
  float r = red[0] + red[1] + red[2] + red[3];
  __syncthreads();
  return r;
}

// Cell pointwise + attention (or final output on step 3). One block per row.
__global__ __launch_bounds__(256) void k_cell(
    const float* __restrict__ gates, const float* __restrict__ qn,
    float* __restrict__ c, float* __restrict__ hc,
    const float* __restrict__ sg, float* __restrict__ attn,
    const float* __restrict__ sm, float* __restrict__ out, int step)
{
  __shared__ float red[4];
  const int b = blockIdx.x, t = threadIdx.x;
  const float* g = gates + (size_t)b * 2048;
  float i0 = g[t],        f0 = g[512 + t], gg0 = g[1024 + t], o0 = g[1536 + t];
  float i1 = g[256 + t],  f1 = g[768 + t], gg1 = g[1280 + t];
  float co0 = step ? c[b * 512 + t] : 0.f;
  float co1 = step ? c[b * 512 + 256 + t] : 0.f;
  float c0 = sigmoidf_(f0) * co0 + sigmoidf_(i0) * tanhf(gg0);
  float c1 = sigmoidf_(f1) * co1 + sigmoidf_(i1) * tanhf(gg1);
  c[b * 512 + t] = c0;
  c[b * 512 + 256 + t] = c1;
  float hcv = sigmoidf_(o0) * tanhf(c0);
  float h = qn[b * 256 + t] + hcv;
  hc[b * 256 + t] = hcv;
  if (step < 3) {
    float dots[5];
    #pragma unroll
    for (int s = 0; s < 5; ++s) dots[s] = block_sum256(h * sg[s * 256 + t], red);
    float m = dots[0];
    #pragma unroll
    for (int s = 1; s < 5; ++s) m = fmaxf(m, dots[s]);
    float sum = 0.f;
    #pragma unroll
    for (int s = 0; s < 5; ++s) sum += __expf(dots[s] - m);
    if (t < 5) {
      float dv = (t == 1) ? dots[1] : (t == 2) ? dots[2] : (t == 3) ? dots[3]
               : (t == 4) ? dots[4] : dots[0];
      attn[b * 8 + t] = __expf(dv - m) / sum;
    }
  } else {
    float tot = block_sum256(h * sm[t], red);
    if (t == 0) out[b] = tot;
  }
}

// ---------------------------------------------------------------------------
extern "C" void kernel_launch(void* const* d_in, const int* in_sizes, int n_in,
                              void* d_out, int out_size, void* d_ws, size_t ws_size,
                              hipStream_t stream)
{
  (void)in_sizes; (void)n_in; (void)out_size; (void)ws_size;
  const int *q_l1 = (const int*)d_in[0], *q_l2 = (const int*)d_in[1];
  const int *q_r1 = (const int*)d_in[2], *q_r2 = (const int*)d_in[3];
  const int *s_l1 = (const int*)d_in[4], *s_l2 = (const int*)d_in[5];
  const int *s_r1 = (const int*)d_in[6], *s_r2 = (const int*)d_in[7];
  // d_in[8..11] = degree vectors, unused by the reference
  const float* emb      = (const float*)d_in[12];
  const float* gcn_w    = (const float*)d_in[13];
  const float* gcn_wb   = (const float*)d_in[14];
  const float* gcn_b    = (const float*)d_in[15];
  const float* hop_gate = (const float*)d_in[16];
  const float* attn_w   = (const float*)d_in[17];
  // attn_b (d_in[18]) cancels in softmax
  const float* p1_w = (const float*)d_in[19];
  const float* p1_b = (const float*)d_in[20];
  const float* p2_w = (const float*)d_in[21];
  const float* p2_b = (const float*)d_in[22];
  const float* ln_g = (const float*)d_in[23];
  const float* ln_b = (const float*)d_in[24];
  const float* w_ih = (const float*)d_in[25];
  const float* w_hh = (const float*)d_in[26];
  const float* b_ih = (const float*)d_in[27];
  const float* b_hh = (const float*)d_in[28];

  char* base = (char*)d_ws;
  size_t off = 0;
  auto alloc = [&](size_t bytes) -> char* {
    char* r = base + off;
    off = (off + bytes + 255) & ~(size_t)255;
    return r;
  };
  float* pr    = (float*)alloc(100001ull * 128 * 4);
  float* pe    = (float*)alloc(100001ull * 128 * 4);
  float* srel  = (float*)alloc(100001ull * 4);
  float* sent  = (float*)alloc(100001ull * 4);
  float* qn    = (float*)alloc(4096ull * 256 * 4);
  float* sn    = (float*)alloc(5 * 256 * 4);
  float* sg    = (float*)alloc(5 * 256 * 4);
  float* sm    = (float*)alloc(256 * 4);
  float* SG2   = (float*)alloc(5 * 2048 * 4);
  float* Wih   = (float*)alloc(2048ull * 256 * 4);
  float* Wc    = (float*)alloc(2048ull * 256 * 4);
  float* Wh1   = (float*)alloc(2048ull * 256 * 4);
  float* bsum  = (float*)alloc(2048 * 4);
  float* gates = (float*)alloc(4096ull * 2048 * 4);
  float* cbuf  = (float*)alloc(4096ull * 512 * 4);
  float* hcb   = (float*)alloc(4096ull * 256 * 4);
  float* attnb = (float*)alloc(4096ull * 8 * 4);

  k_precompute<<<2048, 256, 0, stream>>>(emb, gcn_w, attn_w, pr, pe, srel, sent);
  k_weights<<<2048, 256, 0, stream>>>(w_ih, w_hh, b_ih, b_hh, Wih, Wc, Wh1, bsum);
  k_neighbor<<<4096, 128, 0, stream>>>(q_l1, q_l2, pr, pe, srel, sent, gcn_wb, gcn_b, hop_gate, qn, 0);
  k_neighbor<<<4096, 128, 0, stream>>>(q_r1, q_r2, pr, pe, srel, sent, gcn_wb, gcn_b, hop_gate, qn, 128);
  k_neighbor<<<5, 128, 0, stream>>>(s_l1, s_l2, pr, pe, srel, sent, gcn_wb, gcn_b, hop_gate, sn, 0);
  k_neighbor<<<5, 128, 0, stream>>>(s_r1, s_r2, pr, pe, srel, sent, gcn_wb, gcn_b, hop_gate, sn, 128);
  k_support<<<1, 256, 0, stream>>>(sn, p1_w, p1_b, p2_w, p2_b, ln_g, ln_b, sg, sm);
  k_sg2<<<40, 256, 0, stream>>>(sg, w_hh, SG2);

  for (int step = 0; step < 4; ++step) {
    if (step == 0)
      k_gates<<<2048, 256, 0, stream>>>(qn, Wih, (const float*)nullptr, (const float*)nullptr,
                                        (const float*)nullptr, (const float*)nullptr, bsum, gates);
    else
      k_gates<<<2048, 256, 0, stream>>>(qn, Wc, hcb, Wh1, attnb, SG2, bsum, gates);
    k_cell<<<4096, 256, 0, stream>>>(gates, qn, cbuf, hcb, sg, attnb, sm, (float*)d_out, step);
  }
}

// Round 3
// 900.216 us; speedup vs baseline: 1.8415x; 1.8415x over previous
//
#include <hip/hip_runtime.h>

typedef unsigned short bf16u;
typedef unsigned int u32;
typedef float f32x4 __attribute__((ext_vector_type(4)));
typedef short bf16x8 __attribute__((ext_vector_type(8)));

__device__ inline float sigmoidf_(float x) { return 1.f / (1.f + __expf(-x)); }
__device__ inline bf16u f2b(float f) {
  u32 i = __float_as_uint(f);
  u32 r = (i + 0x7fffu + ((i >> 16) & 1u)) >> 16;
  return (bf16u)r;
}

// ---------------------------------------------------------------------------
// Precompute pr = emb @ gcn_w[:, :128].T, pe = emb @ gcn_w[:,128:].T (fp32),
// and score tables srel = pr . attn_w, sent = pe . attn_w.
__global__ __launch_bounds__(256) void k_precompute(
    const float* __restrict__ emb, const float* __restrict__ gcn_w,
    const float* __restrict__ attn_w,
    float* __restrict__ pr, float* __restrict__ pe,
    float* __restrict__ srel, float* __restrict__ sent)
{
  const int t = threadIdx.x;
  const int which = t >> 7;   // 0: rel half (W cols 0..127), 1: ent half
  const int d = t & 127;
  float wv[128];
  {
    const float4* wrow = (const float4*)(gcn_w + d * 256 + which * 128);
    #pragma unroll
    for (int j = 0; j < 32; ++j) {
      float4 v = wrow[j];
      wv[4*j+0] = v.x; wv[4*j+1] = v.y; wv[4*j+2] = v.z; wv[4*j+3] = v.w;
    }
  }
  const float aw = attn_w[d];
  __shared__ float red[4];
  float* outt = which ? pe : pr;
  float* souts = which ? sent : srel;
  for (int i = blockIdx.x; i < 100001; i += gridDim.x) {
    const float* er = emb + (size_t)i * 128;
    float a0 = 0.f, a1 = 0.f, a2 = 0.f, a3 = 0.f;
    #pragma unroll
    for (int k = 0; k < 128; k += 4) {
      a0 += er[k + 0] * wv[k + 0];
      a1 += er[k + 1] * wv[k + 1];
      a2 += er[k + 2] * wv[k + 2];
      a3 += er[k + 3] * wv[k + 3];
    }
    float v = (a0 + a1) + (a2 + a3);
    outt[(size_t)i * 128 + d] = v;
    float pp = v * aw;
    #pragma unroll
    for (int off = 32; off; off >>= 1) pp += __shfl_down(pp, off, 64);
    __syncthreads();
    if ((t & 63) == 0) red[t >> 6] = pp;
    __syncthreads();
    if ((t & 127) == 0) souts[i] = red[(which << 1)] + red[(which << 1) + 1];
  }
}

// ---------------------------------------------------------------------------
// Weight prep (bf16 packed): WWa[j][0:256]=w_ih; WWb[j][0:256]=w_ih+whh1,
// [256:512]=whh1, [517:544]=0. bsum = b_ih + b_hh (fp32).
__global__ __launch_bounds__(256) void k_weights(
    const float* __restrict__ w_ih, const float* __restrict__ w_hh,
    const float* __restrict__ b_ih, const float* __restrict__ b_hh,
    bf16u* __restrict__ WWa, bf16u* __restrict__ WWb, float* __restrict__ bsum)
{
  const int j = blockIdx.x, k = threadIdx.x;
  float wi = w_ih[j * 256 + k];
  float wh = w_hh[j * 512 + k];
  WWa[(size_t)j * 576 + k] = f2b(wi);
  WWb[(size_t)j * 576 + k] = f2b(wi + wh);
  WWb[(size_t)j * 576 + 256 + k] = f2b(wh);
  if (k < 27) WWb[(size_t)j * 576 + 517 + k] = 0;
  if (k == 0) bsum[j] = b_ih[j] + b_hh[j];
}

// Zero XX pad cols 517..543 (rest of the attn k-chunk).
__global__ __launch_bounds__(64) void k_init(bf16u* __restrict__ XX)
{
  if (threadIdx.x < 27) XX[(size_t)blockIdx.x * 576 + 517 + threadIdx.x] = 0;
}

// ---------------------------------------------------------------------------
// Neighbor pair encoder -> fp32 out[n][coloff+d] and (optional) bf16 XX.
__global__ __launch_bounds__(128) void k_neighbor(
    const int* __restrict__ connA, const int* __restrict__ connB,
    const float* __restrict__ pr, const float* __restrict__ pe,
    const float* __restrict__ srel, const float* __restrict__ sent,
    const float* __restrict__ gcn_wb, const float* __restrict__ gcn_b,
    const float* __restrict__ hop_gate,
    float* __restrict__ out, bf16u* __restrict__ xx, int coloff)
{
  const int n = blockIdx.x, t = threadIdx.x;
  __shared__ int idxA[64][2], idxB[64][2];
  __shared__ float wA[64], wB[64];
  {
    const int hop = t >> 6, nn = t & 63;
    const int* conn = hop ? connB : connA;
    int rel = conn[(n * 64 + nn) * 2 + 0];
    int ent = conn[(n * 64 + nn) * 2 + 1];
    int (*idx)[2] = hop ? idxB : idxA;
    idx[nn][0] = rel; idx[nn][1] = ent;
    float sc = srel[rel] + sent[ent];
    float m = sc;
    #pragma unroll
    for (int off = 32; off; off >>= 1) m = fmaxf(m, __shfl_xor(m, off, 64));
    float e = __expf(sc - m);
    float s = e;
    #pragma unroll
    for (int off = 32; off; off >>= 1) s += __shfl_xor(s, off, 64);
    (hop ? wB : wA)[nn] = e / s;
  }
  __syncthreads();
  const int d = t;                          // 0..127
  float accA = 0.f, accB = 0.f;
  #pragma unroll 4
  for (int k = 0; k < 64; ++k) {
    accA += wA[k] * (pr[(size_t)idxA[k][0] * 128 + d] + pe[(size_t)idxA[k][1] * 128 + d]);
    accB += wB[k] * (pr[(size_t)idxB[k][0] * 128 + d] + pe[(size_t)idxB[k][1] * 128 + d]);
  }
  float bias = gcn_wb[d] + gcn_b[d];
  float g0 = hop_gate[0], g1 = hop_gate[1];
  float mx = fmaxf(g0, g1);
  float e0 = __expf(g0 - mx), e1 = __expf(g1 - mx);
  float inv = 1.f / (e0 + e1);
  float v = e0 * inv * tanhf(bias + accA) + e1 * inv * tanhf(bias + accB);
  out[n * 256 + coloff + d] = v;
  if (xx) xx[(size_t)n * 576 + coloff + d] = f2b(v);
}

// ---------------------------------------------------------------------------
// Support encoder stage 1: h1[r][j] = relu(sn[r] . p1_w[j] + p1_b[j]).
// Grid 40 = 5 rows x 8 chunks of 64 j. 4 lanes cooperate per j.
__global__ __launch_bounds__(256) void k_sup1(
    const float* __restrict__ sn, const float* __restrict__ p1_w,
    const float* __restrict__ p1_b, float* __restrict__ h1)
{
  const int r = blockIdx.x >> 3, j0 = (blockIdx.x & 7) << 6;
  const int t = threadIdx.x;
  __shared__ float xs[256];
  xs[t] = sn[r * 256 + t];
  __syncthreads();
  const int j = j0 + (t >> 2), q = t & 3;
  const float* wr = p1_w + (size_t)j * 256 + q * 64;
  float acc = 0.f;
  #pragma unroll
  for (int k = 0; k < 64; ++k) acc += xs[q * 64 + k] * wr[k];
  acc += __shfl_xor(acc, 1, 64);
  acc += __shfl_xor(acc, 2, 64);
  if (q == 0) h1[r * 512 + j] = fmaxf(acc + p1_b[j], 0.f);
}

// Stage 2: z = h1@p2_w.T + p2_b + sn, then LayerNorm -> sg. One block per row.
__global__ __launch_bounds__(256) void k_sup2(
    const float* __restrict__ sn, const float* __restrict__ h1,
    const float* __restrict__ p2_w, const float* __restrict__ p2_b,
    const float* __restrict__ ln_g, const float* __restrict__ ln_b,
    float* __restrict__ sg)
{
  const int r = blockIdx.x, t = threadIdx.x;
  const int lane = t & 63, wave = t >> 6;
  __shared__ float hs[512];
  __shared__ float zs[256];
  __shared__ float r1[4], r2[4];
  hs[t] = h1[r * 512 + t];
  hs[t + 256] = h1[r * 512 + 256 + t];
  __syncthreads();
  const int q = t & 3;
  #pragma unroll
  for (int jc = 0; jc < 4; ++jc) {
    int j = jc * 64 + (t >> 2);
    const float* wr = p2_w + (size_t)j * 512 + q * 128;
    float acc = 0.f;
    #pragma unroll
    for (int k = 0; k < 128; ++k) acc += hs[q * 128 + k] * wr[k];
    acc += __shfl_xor(acc, 1, 64);
    acc += __shfl_xor(acc, 2, 64);
    if (q == 0) zs[j] = acc + p2_b[j] + sn[r * 256 + j];
  }
  __syncthreads();
  float v = zs[t];
  float s1 = v, s2 = v * v;
  #pragma unroll
  for (int off = 32; off; off >>= 1) { s1 += __shfl_xor(s1, off, 64); s2 += __shfl_xor(s2, off, 64); }
  if (lane == 0) { r1[wave] = s1; r2[wave] = s2; }
  __syncthreads();
  float S1 = r1[0] + r1[1] + r1[2] + r1[3];
  float S2 = r2[0] + r2[1] + r2[2] + r2[3];
  float mu = S1 * (1.f / 256.f);
  float var = S2 * (1.f / 256.f) - mu * mu;
  sg[r * 256 + t] = (v - mu) * rsqrtf(var + 1e-6f) * ln_g[t] + ln_b[t];
}

// ---------------------------------------------------------------------------
// SG2[r][j] = sg[r] . w_hh[j][256:512] -> WWb[j][512+r] (bf16). Block 0 also
// writes sm[t] = mean_r sg[r][t].
__global__ __launch_bounds__(256) void k_sg2(
    const float* __restrict__ sg, const float* __restrict__ w_hh,
    bf16u* __restrict__ WWb, float* __restrict__ sm)
{
  __shared__ float s[5][256];
  const int t = threadIdx.x, lane = t & 63, wave = t >> 6;
  for (int i = t; i < 1280; i += 256) s[i >> 8][i & 255] = sg[i];
  __syncthreads();
  if (blockIdx.x == 0)
    sm[t] = (s[0][t] + s[1][t] + s[2][t] + s[3][t] + s[4][t]) * 0.2f;
  const int base = blockIdx.x * 256;
  for (int oi = wave; oi < 256; oi += 4) {
    int o = base + oi;                    // o = r*2048 + j
    int r = o >> 11, j = o & 2047;
    const float* wr = w_hh + (size_t)j * 512 + 256;
    float acc = 0.f;
    #pragma unroll
    for (int qq = 0; qq < 4; ++qq) acc += s[r][lane + 64*qq] * wr[lane + 64*qq];
    #pragma unroll
    for (int off = 32; off; off >>= 1) acc += __shfl_xor(acc, off, 64);
    if (lane == 0) WWb[(size_t)j * 576 + 512 + r] = f2b(acc);
  }
}

// ---------------------------------------------------------------------------
// gates[4096][2048] = XX[:, :K] @ WW[:, :K].T + bsum, bf16 MFMA 16x16x32.
// 128x128 tile, 4 waves (2x2), each wave 4x4 mfma tiles.
__global__ __launch_bounds__(256) void k_gates_mfma(
    const bf16u* __restrict__ XX, const bf16u* __restrict__ WW,
    const float* __restrict__ bsum, float* __restrict__ gates, int kchunks)
{
  const int t = threadIdx.x;
  const int wave = t >> 6, lane = t & 63;
  const int quad = lane >> 4, l16 = lane & 15;
  const int wm = (wave >> 1) << 6, wn = (wave & 1) << 6;
  const int row0 = (blockIdx.x >> 4) << 7;
  const int col0 = (blockIdx.x & 15) << 7;
  __shared__ short As[128][40];     // 32 bf16 per row + 8 pad (80B rows)
  __shared__ short Bs[128][40];
  f32x4 acc[4][4];
  #pragma unroll
  for (int i = 0; i < 4; ++i)
    #pragma unroll
    for (int j = 0; j < 4; ++j) acc[i][j] = (f32x4){0.f, 0.f, 0.f, 0.f};

  const int srow = t >> 1, shalf = t & 1;
  const bf16u* xp = XX + (size_t)(row0 + srow) * 576 + shalf * 16;
  const bf16u* wp = WW + (size_t)(col0 + srow) * 576 + shalf * 16;

  for (int kc = 0; kc < kchunks; ++kc) {
    uint4 x0 = *(const uint4*)(xp + kc * 32);
    uint4 x1 = *(const uint4*)(xp + kc * 32 + 8);
    uint4 w0 = *(const uint4*)(wp + kc * 32);
    uint4 w1 = *(const uint4*)(wp + kc * 32 + 8);
    __syncthreads();
    *(uint4*)&As[srow][shalf * 16] = x0;
    *(uint4*)&As[srow][shalf * 16 + 8] = x1;
    *(uint4*)&Bs[srow][shalf * 16] = w0;
    *(uint4*)&Bs[srow][shalf * 16 + 8] = w1;
    __syncthreads();
    bf16x8 af[4], bfr[4];
    #pragma unroll
    for (int i = 0; i < 4; ++i)
      af[i] = *(const bf16x8*)&As[wm + i * 16 + l16][quad * 8];
    #pragma unroll
    for (int j = 0; j < 4; ++j)
      bfr[j] = *(const bf16x8*)&Bs[wn + j * 16 + l16][quad * 8];
    #pragma unroll
    for (int i = 0; i < 4; ++i)
      #pragma unroll
      for (int j = 0; j < 4; ++j)
        acc[i][j] = __builtin_amdgcn_mfma_f32_16x16x32_bf16(af[i], bfr[j], acc[i][j], 0, 0, 0);
  }

  #pragma unroll
  for (int j = 0; j < 4; ++j) {
    const int col = col0 + wn + j * 16 + l16;
    const float bs = bsum[col];
    #pragma unroll
    for (int i = 0; i < 4; ++i) {
      #pragma unroll
      for (int r = 0; r < 4; ++r) {
        int row = row0 + wm + i * 16 + quad * 4 + r;
        gates[(size_t)row * 2048 + col] = acc[i][j][r] + bs;
      }
    }
  }
}

// ---------------------------------------------------------------------------
__device__ inline float block_sum256(float v, float* red) {
  const int lane = threadIdx.x & 63, wave = threadIdx.x >> 6;
  #pragma unroll
  for (int off = 32; off; off >>= 1) v += __shfl_xor(v, off, 64);
  if (lane == 0) red[wave] = v;
  __syncthreads();
  float r = red[0] + red[1] + red[2] + red[3];
  __syncthreads();
  return r;
}

// Cell pointwise + attention (writes bf16 hc/attn into XX) or final output.
__global__ __launch_bounds__(256) void k_cell(
    const float* __restrict__ gates, const float* __restrict__ qn,
    float* __restrict__ c, bf16u* __restrict__ XX,
    const float* __restrict__ sg, const float* __restrict__ sm,
    float* __restrict__ out, int step)
{
  __shared__ float red[4];
  const int b = blockIdx.x, t = threadIdx.x;
  const float* g = gates + (size_t)b * 2048;
  float i0 = g[t],        f0 = g[512 + t], gg0 = g[1024 + t], o0 = g[1536 + t];
  float i1 = g[256 + t],  f1 = g[768 + t], gg1 = g[1280 + t];
  float co0 = step ? c[b * 512 + t] : 0.f;
  float co1 = step ? c[b * 512 + 256 + t] : 0.f;
  float c0 = sigmoidf_(f0) * co0 + sigmoidf_(i0) * tanhf(gg0);
  float c1 = sigmoidf_(f1) * co1 + sigmoidf_(i1) * tanhf(gg1);
  c[b * 512 + t] = c0;
  c[b * 512 + 256 + t] = c1;
  float hcv = sigmoidf_(o0) * tanhf(c0);
  float h = qn[b * 256 + t] + hcv;
  if (step < 3) {
    XX[(size_t)b * 576 + 256 + t] = f2b(hcv);
    float dots[5];
    #pragma unroll
    for (int s = 0; s < 5; ++s) dots[s] = block_sum256(h * sg[s * 256 + t], red);
    float m = dots[0];
    #pragma unroll
    for (int s = 1; s < 5; ++s) m = fmaxf(m, dots[s]);
    float sum = 0.f;
    #pragma unroll
    for (int s = 0; s < 5; ++s) sum += __expf(dots[s] - m);
    if (t < 5) {
      float dv = (t == 1) ? dots[1] : (t == 2) ? dots[2] : (t == 3) ? dots[3]
               : (t == 4) ? dots[4] : dots[0];
      XX[(size_t)b * 576 + 512 + t] = f2b(__expf(dv - m) / sum);
    }
  } else {
    float tot = block_sum256(h * sm[t], red);
    if (t == 0) out[b] = tot;
  }
}

// ---------------------------------------------------------------------------
extern "C" void kernel_launch(void* const* d_in, const int* in_sizes, int n_in,
                              void* d_out, int out_size, void* d_ws, size_t ws_size,
                              hipStream_t stream)
{
  (void)in_sizes; (void)n_in; (void)out_size; (void)ws_size;
  const int *q_l1 = (const int*)d_in[0], *q_l2 = (const int*)d_in[1];
  const int *q_r1 = (const int*)d_in[2], *q_r2 = (const int*)d_in[3];
  const int *s_l1 = (const int*)d_in[4], *s_l2 = (const int*)d_in[5];
  const int *s_r1 = (const int*)d_in[6], *s_r2 = (const int*)d_in[7];
  const float* emb      = (const float*)d_in[12];
  const float* gcn_w    = (const float*)d_in[13];
  const float* gcn_wb   = (const float*)d_in[14];
  const float* gcn_b    = (const float*)d_in[15];
  const float* hop_gate = (const float*)d_in[16];
  const float* attn_w   = (const float*)d_in[17];
  const float* p1_w = (const float*)d_in[19];
  const float* p1_b = (const float*)d_in[20];
  const float* p2_w = (const float*)d_in[21];
  const float* p2_b = (const float*)d_in[22];
  const float* ln_g = (const float*)d_in[23];
  const float* ln_b = (const float*)d_in[24];
  const float* w_ih = (const float*)d_in[25];
  const float* w_hh = (const float*)d_in[26];
  const float* b_ih = (const float*)d_in[27];
  const float* b_hh = (const float*)d_in[28];

  char* base = (char*)d_ws;
  size_t off = 0;
  auto alloc = [&](size_t bytes) -> char* {
    char* r = base + off;
    off = (off + bytes + 255) & ~(size_t)255;
    return r;
  };
  float* pr    = (float*)alloc(100001ull * 128 * 4);
  float* pe    = (float*)alloc(100001ull * 128 * 4);
  float* srel  = (float*)alloc(100001ull * 4);
  float* sent  = (float*)alloc(100001ull * 4);
  float* qn    = (float*)alloc(4096ull * 256 * 4);
  float* sn    = (float*)alloc(5 * 256 * 4);
  float* sg    = (float*)alloc(5 * 256 * 4);
  float* sm    = (float*)alloc(256 * 4);
  float* h1b   = (float*)alloc(5 * 512 * 4);
  bf16u* XX    = (bf16u*)alloc(4096ull * 576 * 2);
  bf16u* WWa   = (bf16u*)alloc(2048ull * 576 * 2);
  bf16u* WWb   = (bf16u*)alloc(2048ull * 576 * 2);
  float* bsum  = (float*)alloc(2048 * 4);
  float* gates = (float*)alloc(4096ull * 2048 * 4);
  float* cbuf  = (float*)alloc(4096ull * 512 * 4);

  k_precompute<<<2048, 256, 0, stream>>>(emb, gcn_w, attn_w, pr, pe, srel, sent);
  k_weights<<<2048, 256, 0, stream>>>(w_ih, w_hh, b_ih, b_hh, WWa, WWb, bsum);
  k_init<<<4096, 64, 0, stream>>>(XX);
  k_neighbor<<<4096, 128, 0, stream>>>(q_l1, q_l2, pr, pe, srel, sent, gcn_wb, gcn_b, hop_gate, qn, XX, 0);
  k_neighbor<<<4096, 128, 0, stream>>>(q_r1, q_r2, pr, pe, srel, sent, gcn_wb, gcn_b, hop_gate, qn, XX, 128);
  k_neighbor<<<5, 128, 0, stream>>>(s_l1, s_l2, pr, pe, srel, sent, gcn_wb, gcn_b, hop_gate, sn, (bf16u*)nullptr, 0);
  k_neighbor<<<5, 128, 0, stream>>>(s_r1, s_r2, pr, pe, srel, sent, gcn_wb, gcn_b, hop_gate, sn, (bf16u*)nullptr, 128);
  k_sup1<<<40, 256, 0, stream>>>(sn, p1_w, p1_b, h1b);
  k_sup2<<<5, 256, 0, stream>>>(sn, h1b, p2_w, p2_b, ln_g, ln_b, sg);
  k_sg2<<<40, 256, 0, stream>>>(sg, w_hh, WWb, sm);

  for (int step = 0; step < 4; ++step) {
    if (step == 0)
      k_gates_mfma<<<512, 256, 0, stream>>>(XX, WWa, bsum, gates, 8);
    else
      k_gates_mfma<<<512, 256, 0, stream>>>(XX, WWb, bsum, gates, 17);
    k_cell<<<4096, 256, 0, stream>>>(gates, qn, cbuf, XX, sg, sm, (float*)d_out, step);
  }
}

// Round 4
// 562.030 us; speedup vs baseline: 2.9496x; 1.6017x over previous
//
#include <hip/hip_runtime.h>

typedef unsigned short bf16u;
typedef unsigned int u32;
typedef float f32x4 __attribute__((ext_vector_type(4)));
typedef short bf16x8 __attribute__((ext_vector_type(8)));

__device__ inline float sigmoidf_(float x) { return 1.f / (1.f + __expf(-x)); }
__device__ inline float b2f(bf16u u) { return __uint_as_float(((u32)u) << 16); }
__device__ inline bf16u f2b(float f) {
  u32 i = __float_as_uint(f);
  u32 r = (i + 0x7fffu + ((i >> 16) & 1u)) >> 16;
  return (bf16u)r;
}

// ---------------------------------------------------------------------------
// pr/pe tables via tiled fp32 GEMM: out[i][o] = emb[i] . V[o], where
// V[o][k] = gcn_w[(o&127)][ (o>>7)*128 + k ].  o<128 -> pr, else pe. bf16 out.
// 64x64 tile, 256 threads, 4x4 acc/thread, K=128 in 4 chunks of 32.
__global__ __launch_bounds__(256) void k_pre_gemm(
    const float* __restrict__ emb, const float* __restrict__ gcn_w,
    bf16u* __restrict__ pr, bf16u* __restrict__ pe)
{
  const int t = threadIdx.x;
  const int tx = t & 15, ty = t >> 4;
  const int row0 = (blockIdx.x >> 2) << 6;
  const int col0 = (blockIdx.x & 3) << 6;
  __shared__ float xs[32][68];
  __shared__ float ws[32][68];
  float acc[4][4];
  #pragma unroll
  for (int i = 0; i < 4; ++i)
    #pragma unroll
    for (int j = 0; j < 4; ++j) acc[i][j] = 0.f;

  for (int k0 = 0; k0 < 128; k0 += 32) {
    __syncthreads();
    #pragma unroll
    for (int s_ = 0; s_ < 2; ++s_) {
      int f4 = t + s_ * 256;           // 0..511
      int row = f4 >> 3;               // 0..63
      int kq = (f4 & 7) << 2;          // 0..28
      int ar = row0 + row; if (ar > 100000) ar = 100000;
      float4 v = *(const float4*)&emb[(size_t)ar * 128 + k0 + kq];
      xs[kq+0][row] = v.x; xs[kq+1][row] = v.y; xs[kq+2][row] = v.z; xs[kq+3][row] = v.w;
      int o = col0 + row;
      const float* wrow = gcn_w + ((o & 127) << 8) + ((o >> 7) << 7);
      float4 u = *(const float4*)&wrow[k0 + kq];
      ws[kq+0][row] = u.x; ws[kq+1][row] = u.y; ws[kq+2][row] = u.z; ws[kq+3][row] = u.w;
    }
    __syncthreads();
    #pragma unroll
    for (int k = 0; k < 32; ++k) {
      float4 av = *(const float4*)&xs[k][ty << 2];
      float4 bv = *(const float4*)&ws[k][tx << 2];
      float a_[4] = {av.x, av.y, av.z, av.w};
      float b_[4] = {bv.x, bv.y, bv.z, bv.w};
      #pragma unroll
      for (int i = 0; i < 4; ++i)
        #pragma unroll
        for (int j = 0; j < 4; ++j) acc[i][j] += a_[i] * b_[j];
    }
  }
  const int o0 = col0 + (tx << 2);
  bf16u* tab = (o0 < 128) ? pr : pe;
  const int cd = o0 & 127;
  #pragma unroll
  for (int i = 0; i < 4; ++i) {
    int row = row0 + (ty << 2) + i;
    if (row <= 100000) {
      ushort4 pk;
      pk.x = f2b(acc[i][0]); pk.y = f2b(acc[i][1]);
      pk.z = f2b(acc[i][2]); pk.w = f2b(acc[i][3]);
      *(ushort4*)&tab[(size_t)row * 128 + cd] = pk;
    }
  }
}

// ---------------------------------------------------------------------------
// uvec[o] = sum_d gcn_w[d][(o>>7)*128 + (o&127)] * attn_w[d]   (one block)
__global__ __launch_bounds__(256) void k_uvec(
    const float* __restrict__ gcn_w, const float* __restrict__ attn_w,
    float* __restrict__ uvec)
{
  const int o = threadIdx.x;
  const int col = ((o >> 7) << 7) + (o & 127);
  float acc = 0.f;
  for (int d = 0; d < 128; ++d) acc += gcn_w[d * 256 + col] * attn_w[d];
  uvec[o] = acc;
}

// srel[i] = emb[i] . uvec[0:128]; sent[i] = emb[i] . uvec[128:256]
__global__ __launch_bounds__(256) void k_scores(
    const float* __restrict__ emb, const float* __restrict__ uvec,
    float* __restrict__ srel, float* __restrict__ sent)
{
  __shared__ float us[256];
  const int t = threadIdx.x;
  us[t] = uvec[t];
  __syncthreads();
  const int i = blockIdx.x * 256 + t;
  if (i > 100000) return;
  const float4* er = (const float4*)(emb + (size_t)i * 128);
  float a0 = 0.f, a1 = 0.f;
  #pragma unroll
  for (int k = 0; k < 32; ++k) {
    float4 v = er[k];
    a0 += v.x * us[4*k+0] + v.y * us[4*k+1] + v.z * us[4*k+2] + v.w * us[4*k+3];
    a1 += v.x * us[128+4*k+0] + v.y * us[128+4*k+1] + v.z * us[128+4*k+2] + v.w * us[128+4*k+3];
  }
  srel[i] = a0; sent[i] = a1;
}

// ---------------------------------------------------------------------------
// Weight prep (bf16 packed): WWa[j][0:256]=w_ih; WWb[j][0:256]=w_ih+whh1,
// [256:512]=whh1, [517:544]=0. bsum = b_ih + b_hh (fp32).
__global__ __launch_bounds__(256) void k_weights(
    const float* __restrict__ w_ih, const float* __restrict__ w_hh,
    const float* __restrict__ b_ih, const float* __restrict__ b_hh,
    bf16u* __restrict__ WWa, bf16u* __restrict__ WWb, float* __restrict__ bsum)
{
  const int j = blockIdx.x, k = threadIdx.x;
  float wi = w_ih[j * 256 + k];
  float wh = w_hh[j * 512 + k];
  WWa[(size_t)j * 576 + k] = f2b(wi);
  WWb[(size_t)j * 576 + k] = f2b(wi + wh);
  WWb[(size_t)j * 576 + 256 + k] = f2b(wh);
  if (k < 27) WWb[(size_t)j * 576 + 517 + k] = 0;
  if (k == 0) bsum[j] = b_ih[j] + b_hh[j];
}

// Zero XX pad cols 517..543.
__global__ __launch_bounds__(64) void k_init(bf16u* __restrict__ XX)
{
  if (threadIdx.x < 27) XX[(size_t)blockIdx.x * 576 + 517 + threadIdx.x] = 0;
}

// ---------------------------------------------------------------------------
// Neighbor pair encoder (bf16 tables) -> fp32 out and (optional) bf16 XX.
__global__ __launch_bounds__(128) void k_neighbor(
    const int* __restrict__ connA, const int* __restrict__ connB,
    const bf16u* __restrict__ pr, const bf16u* __restrict__ pe,
    const float* __restrict__ srel, const float* __restrict__ sent,
    const float* __restrict__ gcn_wb, const float* __restrict__ gcn_b,
    const float* __restrict__ hop_gate,
    float* __restrict__ out, bf16u* __restrict__ xx, int coloff)
{
  const int n = blockIdx.x, t = threadIdx.x;
  __shared__ int idxA[64][2], idxB[64][2];
  __shared__ float wA[64], wB[64];
  {
    const int hop = t >> 6, nn = t & 63;
    const int* conn = hop ? connB : connA;
    int rel = conn[(n * 64 + nn) * 2 + 0];
    int ent = conn[(n * 64 + nn) * 2 + 1];
    int (*idx)[2] = hop ? idxB : idxA;
    idx[nn][0] = rel; idx[nn][1] = ent;
    float sc = srel[rel] + sent[ent];
    float m = sc;
    #pragma unroll
    for (int off = 32; off; off >>= 1) m = fmaxf(m, __shfl_xor(m, off, 64));
    float e = __expf(sc - m);
    float s = e;
    #pragma unroll
    for (int off = 32; off; off >>= 1) s += __shfl_xor(s, off, 64);
    (hop ? wB : wA)[nn] = e / s;
  }
  __syncthreads();
  const int d = t;                          // 0..127
  float accA = 0.f, accB = 0.f;
  #pragma unroll 4
  for (int k = 0; k < 64; ++k) {
    accA += wA[k] * (b2f(pr[(size_t)idxA[k][0] * 128 + d]) + b2f(pe[(size_t)idxA[k][1] * 128 + d]));
    accB += wB[k] * (b2f(pr[(size_t)idxB[k][0] * 128 + d]) + b2f(pe[(size_t)idxB[k][1] * 128 + d]));
  }
  float bias = gcn_wb[d] + gcn_b[d];
  float g0 = hop_gate[0], g1 = hop_gate[1];
  float mx = fmaxf(g0, g1);
  float e0 = __expf(g0 - mx), e1 = __expf(g1 - mx);
  float inv = 1.f / (e0 + e1);
  float v = e0 * inv * tanhf(bias + accA) + e1 * inv * tanhf(bias + accB);
  out[n * 256 + coloff + d] = v;
  if (xx) xx[(size_t)n * 576 + coloff + d] = f2b(v);
}

// ---------------------------------------------------------------------------
// Support encoder stage 1: h1[r][j] = relu(sn[r] . p1_w[j] + p1_b[j]).
__global__ __launch_bounds__(256) void k_sup1(
    const float* __restrict__ sn, const float* __restrict__ p1_w,
    const float* __restrict__ p1_b, float* __restrict__ h1)
{
  const int r = blockIdx.x >> 3, j0 = (blockIdx.x & 7) << 6;
  const int t = threadIdx.x;
  __shared__ float xs[256];
  xs[t] = sn[r * 256 + t];
  __syncthreads();
  const int j = j0 + (t >> 2), q = t & 3;
  const float* wr = p1_w + (size_t)j * 256 + q * 64;
  float acc = 0.f;
  #pragma unroll
  for (int k = 0; k < 64; ++k) acc += xs[q * 64 + k] * wr[k];
  acc += __shfl_xor(acc, 1, 64);
  acc += __shfl_xor(acc, 2, 64);
  if (q == 0) h1[r * 512 + j] = fmaxf(acc + p1_b[j], 0.f);
}

// Stage 2: z = h1@p2_w.T + p2_b + sn, then LayerNorm -> sg. One block per row.
__global__ __launch_bounds__(256) void k_sup2(
    const float* __restrict__ sn, const float* __restrict__ h1,
    const float* __restrict__ p2_w, const float* __restrict__ p2_b,
    const float* __restrict__ ln_g, const float* __restrict__ ln_b,
    float* __restrict__ sg)
{
  const int r = blockIdx.x, t = threadIdx.x;
  const int lane = t & 63, wave = t >> 6;
  __shared__ float hs[512];
  __shared__ float zs[256];
  __shared__ float r1[4], r2[4];
  hs[t] = h1[r * 512 + t];
  hs[t + 256] = h1[r * 512 + 256 + t];
  __syncthreads();
  const int q = t & 3;
  #pragma unroll
  for (int jc = 0; jc < 4; ++jc) {
    int j = jc * 64 + (t >> 2);
    const float* wr = p2_w + (size_t)j * 512 + q * 128;
    float acc = 0.f;
    #pragma unroll
    for (int k = 0; k < 128; ++k) acc += hs[q * 128 + k] * wr[k];
    acc += __shfl_xor(acc, 1, 64);
    acc += __shfl_xor(acc, 2, 64);
    if (q == 0) zs[j] = acc + p2_b[j] + sn[r * 256 + j];
  }
  __syncthreads();
  float v = zs[t];
  float s1 = v, s2 = v * v;
  #pragma unroll
  for (int off = 32; off; off >>= 1) { s1 += __shfl_xor(s1, off, 64); s2 += __shfl_xor(s2, off, 64); }
  if (lane == 0) { r1[wave] = s1; r2[wave] = s2; }
  __syncthreads();
  float S1 = r1[0] + r1[1] + r1[2] + r1[3];
  float S2 = r2[0] + r2[1] + r2[2] + r2[3];
  float mu = S1 * (1.f / 256.f);
  float var = S2 * (1.f / 256.f) - mu * mu;
  sg[r * 256 + t] = (v - mu) * rsqrtf(var + 1e-6f) * ln_g[t] + ln_b[t];
}

// ---------------------------------------------------------------------------
// SG2[r][j] = sg[r] . w_hh[j][256:512] -> WWb[j][512+r] (bf16). Block 0 also
// writes sm[t] = mean_r sg[r][t].
__global__ __launch_bounds__(256) void k_sg2(
    const float* __restrict__ sg, const float* __restrict__ w_hh,
    bf16u* __restrict__ WWb, float* __restrict__ sm)
{
  __shared__ float s[5][256];
  const int t = threadIdx.x, lane = t & 63, wave = t >> 6;
  for (int i = t; i < 1280; i += 256) s[i >> 8][i & 255] = sg[i];
  __syncthreads();
  if (blockIdx.x == 0)
    sm[t] = (s[0][t] + s[1][t] + s[2][t] + s[3][t] + s[4][t]) * 0.2f;
  const int base = blockIdx.x * 256;
  for (int oi = wave; oi < 256; oi += 4) {
    int o = base + oi;                    // o = r*2048 + j
    int r = o >> 11, j = o & 2047;
    const float* wr = w_hh + (size_t)j * 512 + 256;
    float acc = 0.f;
    #pragma unroll
    for (int qq = 0; qq < 4; ++qq) acc += s[r][lane + 64*qq] * wr[lane + 64*qq];
    #pragma unroll
    for (int off = 32; off; off >>= 1) acc += __shfl_xor(acc, off, 64);
    if (lane == 0) WWb[(size_t)j * 576 + 512 + r] = f2b(acc);
  }
}

// ---------------------------------------------------------------------------
// gates[4096][2048] = XX[:, :K] @ WW[:, :K].T + bsum, bf16 MFMA 16x16x32.
__global__ __launch_bounds__(256) void k_gates_mfma(
    const bf16u* __restrict__ XX, const bf16u* __restrict__ WW,
    const float* __restrict__ bsum, float* __restrict__ gates, int kchunks)
{
  const int t = threadIdx.x;
  const int wave = t >> 6, lane = t & 63;
  const int quad = lane >> 4, l16 = lane & 15;
  const int wm = (wave >> 1) << 6, wn = (wave & 1) << 6;
  const int row0 = (blockIdx.x >> 4) << 7;
  const int col0 = (blockIdx.x & 15) << 7;
  __shared__ short As[128][40];
  __shared__ short Bs[128][40];
  f32x4 acc[4][4];
  #pragma unroll
  for (int i = 0; i < 4; ++i)
    #pragma unroll
    for (int j = 0; j < 4; ++j) acc[i][j] = (f32x4){0.f, 0.f, 0.f, 0.f};

  const int srow = t >> 1, shalf = t & 1;
  const bf16u* xp = XX + (size_t)(row0 + srow) * 576 + shalf * 16;
  const bf16u* wp = WW + (size_t)(col0 + srow) * 576 + shalf * 16;

  for (int kc = 0; kc < kchunks; ++kc) {
    uint4 x0 = *(const uint4*)(xp + kc * 32);
    uint4 x1 = *(const uint4*)(xp + kc * 32 + 8);
    uint4 w0 = *(const uint4*)(wp + kc * 32);
    uint4 w1 = *(const uint4*)(wp + kc * 32 + 8);
    __syncthreads();
    *(uint4*)&As[srow][shalf * 16] = x0;
    *(uint4*)&As[srow][shalf * 16 + 8] = x1;
    *(uint4*)&Bs[srow][shalf * 16] = w0;
    *(uint4*)&Bs[srow][shalf * 16 + 8] = w1;
    __syncthreads();
    bf16x8 af[4], bfr[4];
    #pragma unroll
    for (int i = 0; i < 4; ++i)
      af[i] = *(const bf16x8*)&As[wm + i * 16 + l16][quad * 8];
    #pragma unroll
    for (int j = 0; j < 4; ++j)
      bfr[j] = *(const bf16x8*)&Bs[wn + j * 16 + l16][quad * 8];
    #pragma unroll
    for (int i = 0; i < 4; ++i)
      #pragma unroll
      for (int j = 0; j < 4; ++j)
        acc[i][j] = __builtin_amdgcn_mfma_f32_16x16x32_bf16(af[i], bfr[j], acc[i][j], 0, 0, 0);
  }

  #pragma unroll
  for (int j = 0; j < 4; ++j) {
    const int col = col0 + wn + j * 16 + l16;
    const float bs = bsum[col];
    #pragma unroll
    for (int i = 0; i < 4; ++i) {
      #pragma unroll
      for (int r = 0; r < 4; ++r) {
        int row = row0 + wm + i * 16 + quad * 4 + r;
        gates[(size_t)row * 2048 + col] = acc[i][j][r] + bs;
      }
    }
  }
}

// ---------------------------------------------------------------------------
__device__ inline float block_sum256(float v, float* red) {
  const int lane = threadIdx.x & 63, wave = threadIdx.x >> 6;
  #pragma unroll
  for (int off = 32; off; off >>= 1) v += __shfl_xor(v, off, 64);
  if (lane == 0) red[wave] = v;
  __syncthreads();
  float r = red[0] + red[1] + red[2] + red[3];
  __syncthreads();
  return r;
}

// Cell pointwise + attention (writes bf16 hc/attn into XX) or final output.
__global__ __launch_bounds__(256) void k_cell(
    const float* __restrict__ gates, const float* __restrict__ qn,
    float* __restrict__ c, bf16u* __restrict__ XX,
    const float* __restrict__ sg, const float* __restrict__ sm,
    float* __restrict__ out, int step)
{
  __shared__ float red[4];
  const int b = blockIdx.x, t = threadIdx.x;
  const float* g = gates + (size_t)b * 2048;
  float i0 = g[t],        f0 = g[512 + t], gg0 = g[1024 + t], o0 = g[1536 + t];
  float i1 = g[256 + t],  f1 = g[768 + t], gg1 = g[1280 + t];
  float co0 = step ? c[b * 512 + t] : 0.f;
  float co1 = step ? c[b * 512 + 256 + t] : 0.f;
  float c0 = sigmoidf_(f0) * co0 + sigmoidf_(i0) * tanhf(gg0);
  float c1 = sigmoidf_(f1) * co1 + sigmoidf_(i1) * tanhf(gg1);
  c[b * 512 + t] = c0;
  c[b * 512 + 256 + t] = c1;
  float hcv = sigmoidf_(o0) * tanhf(c0);
  float h = qn[b * 256 + t] + hcv;
  if (step < 3) {
    XX[(size_t)b * 576 + 256 + t] = f2b(hcv);
    float dots[5];
    #pragma unroll
    for (int s = 0; s < 5; ++s) dots[s] = block_sum256(h * sg[s * 256 + t], red);
    float m = dots[0];
    #pragma unroll
    for (int s = 1; s < 5; ++s) m = fmaxf(m, dots[s]);
    float sum = 0.f;
    #pragma unroll
    for (int s = 0; s < 5; ++s) sum += __expf(dots[s] - m);
    if (t < 5) {
      float dv = (t == 1) ? dots[1] : (t == 2) ? dots[2] : (t == 3) ? dots[3]
               : (t == 4) ? dots[4] : dots[0];
      XX[(size_t)b * 576 + 512 + t] = f2b(__expf(dv - m) / sum);
    }
  } else {
    float tot = block_sum256(h * sm[t], red);
    if (t == 0) out[b] = tot;
  }
}

// ---------------------------------------------------------------------------
extern "C" void kernel_launch(void* const* d_in, const int* in_sizes, int n_in,
                              void* d_out, int out_size, void* d_ws, size_t ws_size,
                              hipStream_t stream)
{
  (void)in_sizes; (void)n_in; (void)out_size; (void)ws_size;
  const int *q_l1 = (const int*)d_in[0], *q_l2 = (const int*)d_in[1];
  const int *q_r1 = (const int*)d_in[2], *q_r2 = (const int*)d_in[3];
  const int *s_l1 = (const int*)d_in[4], *s_l2 = (const int*)d_in[5];
  const int *s_r1 = (const int*)d_in[6], *s_r2 = (const int*)d_in[7];
  const float* emb      = (const float*)d_in[12];
  const float* gcn_w    = (const float*)d_in[13];
  const float* gcn_wb   = (const float*)d_in[14];
  const float* gcn_b    = (const float*)d_in[15];
  const float* hop_gate = (const float*)d_in[16];
  const float* attn_w   = (const float*)d_in[17];
  const float* p1_w = (const float*)d_in[19];
  const float* p1_b = (const float*)d_in[20];
  const float* p2_w = (const float*)d_in[21];
  const float* p2_b = (const float*)d_in[22];
  const float* ln_g = (const float*)d_in[23];
  const float* ln_b = (const float*)d_in[24];
  const float* w_ih = (const float*)d_in[25];
  const float* w_hh = (const float*)d_in[26];
  const float* b_ih = (const float*)d_in[27];
  const float* b_hh = (const float*)d_in[28];

  char* base = (char*)d_ws;
  size_t off = 0;
  auto alloc = [&](size_t bytes) -> char* {
    char* r = base + off;
    off = (off + bytes + 255) & ~(size_t)255;
    return r;
  };
  bf16u* pr    = (bf16u*)alloc(100001ull * 128 * 2);
  bf16u* pe    = (bf16u*)alloc(100001ull * 128 * 2);
  float* srel  = (float*)alloc(100001ull * 4);
  float* sent  = (float*)alloc(100001ull * 4);
  float* uvec  = (float*)alloc(256 * 4);
  float* qn    = (float*)alloc(4096ull * 256 * 4);
  float* sn    = (float*)alloc(5 * 256 * 4);
  float* sg    = (float*)alloc(5 * 256 * 4);
  float* sm    = (float*)alloc(256 * 4);
  float* h1b   = (float*)alloc(5 * 512 * 4);
  bf16u* XX    = (bf16u*)alloc(4096ull * 576 * 2);
  bf16u* WWa   = (bf16u*)alloc(2048ull * 576 * 2);
  bf16u* WWb   = (bf16u*)alloc(2048ull * 576 * 2);
  float* bsum  = (float*)alloc(2048 * 4);
  float* gates = (float*)alloc(4096ull * 2048 * 4);
  float* cbuf  = (float*)alloc(4096ull * 512 * 4);

  k_pre_gemm<<<1563 * 4, 256, 0, stream>>>(emb, gcn_w, pr, pe);
  k_uvec<<<1, 256, 0, stream>>>(gcn_w, attn_w, uvec);
  k_scores<<<392, 256, 0, stream>>>(emb, uvec, srel, sent);
  k_weights<<<2048, 256, 0, stream>>>(w_ih, w_hh, b_ih, b_hh, WWa, WWb, bsum);
  k_init<<<4096, 64, 0, stream>>>(XX);
  k_neighbor<<<4096, 128, 0, stream>>>(q_l1, q_l2, pr, pe, srel, sent, gcn_wb, gcn_b, hop_gate, qn, XX, 0);
  k_neighbor<<<4096, 128, 0, stream>>>(q_r1, q_r2, pr, pe, srel, sent, gcn_wb, gcn_b, hop_gate, qn, XX, 128);
  k_neighbor<<<5, 128, 0, stream>>>(s_l1, s_l2, pr, pe, srel, sent, gcn_wb, gcn_b, hop_gate, sn, (bf16u*)nullptr, 0);
  k_neighbor<<<5, 128, 0, stream>>>(s_r1, s_r2, pr, pe, srel, sent, gcn_wb, gcn_b, hop_gate, sn, (bf16u*)nullptr, 128);
  k_sup1<<<40, 256, 0, stream>>>(sn, p1_w, p1_b, h1b);
  k_sup2<<<5, 256, 0, stream>>>(sn, h1b, p2_w, p2_b, ln_g, ln_b, sg);
  k_sg2<<<40, 256, 0, stream>>>(sg, w_hh, WWb, sm);

  for (int step = 0; step < 4; ++step) {
    if (step == 0)
      k_gates_mfma<<<512, 256, 0, stream>>>(XX, WWa, bsum, gates, 8);
    else
      k_gates_mfma<<<512, 256, 0, stream>>>(XX, WWb, bsum, gates, 17);
    k_cell<<<4096, 256, 0, stream>>>(gates, qn, cbuf, XX, sg, sm, (float*)d_out, step);
  }
}

// Round 5
// 509.436 us; speedup vs baseline: 3.2541x; 1.1032x over previous
//
#include <hip/hip_runtime.h>

typedef unsigned short bf16u;
typedef unsigned int u32;
typedef float f32x4 __attribute__((ext_vector_type(4)));
typedef short bf16x8 __attribute__((ext_vector_type(8)));

__device__ inline float sigmoidf_(float x) { return 1.f / (1.f + __expf(-x)); }
__device__ inline float b2f(bf16u u) { return __uint_as_float(((u32)u) << 16); }
__device__ inline bf16u f2b(float f) {
  u32 i = __float_as_uint(f);
  u32 r = (i + 0x7fffu + ((i >> 16) & 1u)) >> 16;
  return (bf16u)r;
}

// ---------------------------------------------------------------------------
// Vp[o][k] = bf16(gcn_w[o&127][(o>>7)*128 + k]), o in [0,256), k in [0,128)
__global__ __launch_bounds__(128) void k_vconv(
    const float* __restrict__ gcn_w, bf16u* __restrict__ Vp)
{
  const int o = blockIdx.x, k = threadIdx.x;
  Vp[o * 128 + k] = f2b(gcn_w[(o & 127) * 256 + ((o >> 7) << 7) + k]);
}

// uvec[o] = sum_d gcn_w[d][(o>>7)*128 + (o&127)] * attn_w[d]   (one block)
__global__ __launch_bounds__(256) void k_uvec(
    const float* __restrict__ gcn_w, const float* __restrict__ attn_w,
    float* __restrict__ uvec)
{
  const int o = threadIdx.x;
  const int col = ((o >> 7) << 7) + (o & 127);
  float acc = 0.f;
  for (int d = 0; d < 128; ++d) acc += gcn_w[d * 256 + col] * attn_w[d];
  uvec[o] = acc;
}

// ---------------------------------------------------------------------------
// pr/pe tables via bf16 MFMA GEMM + fused fp32 score GEMV.
// One block: 128 emb rows x 256 out cols, K=128 (whole K in LDS).
__global__ __launch_bounds__(256) void k_pre_gemm(
    const float* __restrict__ emb, const bf16u* __restrict__ Vp,
    const float* __restrict__ uvec,
    bf16u* __restrict__ pr, bf16u* __restrict__ pe,
    float* __restrict__ srel, float* __restrict__ sent)
{
  const int t = threadIdx.x;
  const int row0 = blockIdx.x << 7;
  __shared__ short As[128][136];   // 272B rows: 16B-aligned, 2-way banks (free)
  __shared__ short Bs[256][136];
  __shared__ float us[256];
  us[t] = uvec[t];
  // stage B (coalesced uint4)
  {
    const uint4* src = (const uint4*)Vp;   // 4096 uint4
    #pragma unroll
    for (int s = 0; s < 16; ++s) {
      int f = s * 256 + t;
      int col = f >> 4, q = f & 15;
      *(uint4*)&Bs[col][q * 8] = src[f];
    }
  }
  __syncthreads();                 // us visible
  // stage A (fp32 -> bf16) + fused scores
  #pragma unroll
  for (int s = 0; s < 16; ++s) {
    int f = s * 256 + t;           // float4 index; 32 per row
    int row = f >> 5, q = f & 31;
    int gr = row0 + row; if (gr > 100000) gr = 100000;
    float4 v = *(const float4*)&emb[(size_t)gr * 128 + (q << 2)];
    ushort4 pk;
    pk.x = f2b(v.x); pk.y = f2b(v.y); pk.z = f2b(v.z); pk.w = f2b(v.w);
    *(ushort4*)&As[row][q << 2] = pk;
    float p0 = v.x * us[4*q+0] + v.y * us[4*q+1] + v.z * us[4*q+2] + v.w * us[4*q+3];
    float p1 = v.x * us[128+4*q+0] + v.y * us[128+4*q+1] + v.z * us[128+4*q+2] + v.w * us[128+4*q+3];
    #pragma unroll
    for (int off = 16; off; off >>= 1) {
      p0 += __shfl_xor(p0, off, 64);
      p1 += __shfl_xor(p1, off, 64);
    }
    if ((t & 31) == 0) { srel[gr] = p0; sent[gr] = p1; }
  }
  __syncthreads();
  const int wave = t >> 6, lane = t & 63;
  const int quad = lane >> 4, l16 = lane & 15;
  const int wm = (wave >> 1) << 6, wn = (wave & 1) << 6;
  #pragma unroll
  for (int half = 0; half < 2; ++half) {
    f32x4 acc[4][4];
    #pragma unroll
    for (int i = 0; i < 4; ++i)
      #pragma unroll
      for (int j = 0; j < 4; ++j) acc[i][j] = (f32x4){0.f, 0.f, 0.f, 0.f};
    #pragma unroll
    for (int kc = 0; kc < 4; ++kc) {
      bf16x8 af[4], bfr[4];
      #pragma unroll
      for (int i = 0; i < 4; ++i)
        af[i] = *(const bf16x8*)&As[wm + i * 16 + l16][kc * 32 + quad * 8];
      #pragma unroll
      for (int j = 0; j < 4; ++j)
        bfr[j] = *(const bf16x8*)&Bs[half * 128 + wn + j * 16 + l16][kc * 32 + quad * 8];
      #pragma unroll
      for (int i = 0; i < 4; ++i)
        #pragma unroll
        for (int j = 0; j < 4; ++j)
          acc[i][j] = __builtin_amdgcn_mfma_f32_16x16x32_bf16(af[i], bfr[j], acc[i][j], 0, 0, 0);
    }
    bf16u* tab = half ? pe : pr;
    #pragma unroll
    for (int j = 0; j < 4; ++j) {
      const int col = wn + j * 16 + l16;
      #pragma unroll
      for (int i = 0; i < 4; ++i) {
        #pragma unroll
        for (int r = 0; r < 4; ++r) {
          int row = row0 + wm + i * 16 + quad * 4 + r;
          if (row <= 100000) tab[(size_t)row * 128 + col] = f2b(acc[i][j][r]);
        }
      }
    }
  }
}

// ---------------------------------------------------------------------------
// Weight prep (bf16 packed): WWa[j][0:256]=w_ih; WWb[j][0:256]=w_ih+whh1,
// [256:512]=whh1, [517:544]=0. bsum = b_ih + b_hh (fp32).
__global__ __launch_bounds__(256) void k_weights(
    const float* __restrict__ w_ih, const float* __restrict__ w_hh,
    const float* __restrict__ b_ih, const float* __restrict__ b_hh,
    bf16u* __restrict__ WWa, bf16u* __restrict__ WWb, float* __restrict__ bsum)
{
  const int j = blockIdx.x, k = threadIdx.x;
  float wi = w_ih[j * 256 + k];
  float wh = w_hh[j * 512 + k];
  WWa[(size_t)j * 576 + k] = f2b(wi);
  WWb[(size_t)j * 576 + k] = f2b(wi + wh);
  WWb[(size_t)j * 576 + 256 + k] = f2b(wh);
  if (k < 27) WWb[(size_t)j * 576 + 517 + k] = 0;
  if (k == 0) bsum[j] = b_ih[j] + b_hh[j];
}

// Zero XX pad cols 517..543.
__global__ __launch_bounds__(64) void k_init(bf16u* __restrict__ XX)
{
  if (threadIdx.x < 27) XX[(size_t)blockIdx.x * 576 + 517 + threadIdx.x] = 0;
}

// ---------------------------------------------------------------------------
// Neighbor pair encoder v2: 256 threads, ushort4 gathers, LDS k-group reduce.
__global__ __launch_bounds__(256) void k_neighbor(
    const int* __restrict__ connA, const int* __restrict__ connB,
    const bf16u* __restrict__ pr, const bf16u* __restrict__ pe,
    const float* __restrict__ srel, const float* __restrict__ sent,
    const float* __restrict__ gcn_wb, const float* __restrict__ gcn_b,
    const float* __restrict__ hop_gate,
    float* __restrict__ out, bf16u* __restrict__ xx, int coloff)
{
  const int n = blockIdx.x, t = threadIdx.x;
  __shared__ int idxA[64][2], idxB[64][2];
  __shared__ float wA[64], wB[64];
  __shared__ float red[2][4][32][4];
  if (t < 128) {
    const int hop = t >> 6, nn = t & 63;
    const int* conn = hop ? connB : connA;
    int rel = conn[(n * 64 + nn) * 2 + 0];
    int ent = conn[(n * 64 + nn) * 2 + 1];
    int (*idx)[2] = hop ? idxB : idxA;
    idx[nn][0] = rel; idx[nn][1] = ent;
    float sc = srel[rel] + sent[ent];
    float m = sc;
    #pragma unroll
    for (int off = 32; off; off >>= 1) m = fmaxf(m, __shfl_xor(m, off, 64));
    float e = __expf(sc - m);
    float s = e;
    #pragma unroll
    for (int off = 32; off; off >>= 1) s += __shfl_xor(s, off, 64);
    (hop ? wB : wA)[nn] = e / s;
  }
  __syncthreads();
  {
    const int hop = t >> 7, g = (t >> 5) & 3, p = t & 31;
    const int (*idx)[2] = hop ? idxB : idxA;
    const float* w = hop ? wB : wA;
    float a0 = 0.f, a1 = 0.f, a2 = 0.f, a3 = 0.f;
    #pragma unroll
    for (int kk = 0; kk < 16; ++kk) {
      int k = g + (kk << 2);
      float wk = w[k];
      ushort4 ra = *(const ushort4*)&pr[(size_t)idx[k][0] * 128 + (p << 2)];
      ushort4 rb = *(const ushort4*)&pe[(size_t)idx[k][1] * 128 + (p << 2)];
      a0 += wk * (b2f(ra.x) + b2f(rb.x));
      a1 += wk * (b2f(ra.y) + b2f(rb.y));
      a2 += wk * (b2f(ra.z) + b2f(rb.z));
      a3 += wk * (b2f(ra.w) + b2f(rb.w));
    }
    red[hop][g][p][0] = a0; red[hop][g][p][1] = a1;
    red[hop][g][p][2] = a2; red[hop][g][p][3] = a3;
  }
  __syncthreads();
  if (t < 128) {
    const int d = t, dp = d >> 2, dq = d & 3;
    float accA = red[0][0][dp][dq] + red[0][1][dp][dq] + red[0][2][dp][dq] + red[0][3][dp][dq];
    float accB = red[1][0][dp][dq] + red[1][1][dp][dq] + red[1][2][dp][dq] + red[1][3][dp][dq];
    float bias = gcn_wb[d] + gcn_b[d];
    float g0 = hop_gate[0], g1 = hop_gate[1];
    float mx = fmaxf(g0, g1);
    float e0 = __expf(g0 - mx), e1 = __expf(g1 - mx);
    float inv = 1.f / (e0 + e1);
    float v = e0 * inv * tanhf(bias + accA) + e1 * inv * tanhf(bias + accB);
    out[n * 256 + coloff + d] = v;
    if (xx) xx[(size_t)n * 576 + coloff + d] = f2b(v);
  }
}

// ---------------------------------------------------------------------------
// Support encoder stage 1: h1[r][j] = relu(sn[r] . p1_w[j] + p1_b[j]).
__global__ __launch_bounds__(256) void k_sup1(
    const float* __restrict__ sn, const float* __restrict__ p1_w,
    const float* __restrict__ p1_b, float* __restrict__ h1)
{
  const int r = blockIdx.x >> 3, j0 = (blockIdx.x & 7) << 6;
  const int t = threadIdx.x;
  __shared__ float xs[256];
  xs[t] = sn[r * 256 + t];
  __syncthreads();
  const int j = j0 + (t >> 2), q = t & 3;
  const float* wr = p1_w + (size_t)j * 256 + q * 64;
  float acc = 0.f;
  #pragma unroll
  for (int k = 0; k < 64; ++k) acc += xs[q * 64 + k] * wr[k];
  acc += __shfl_xor(acc, 1, 64);
  acc += __shfl_xor(acc, 2, 64);
  if (q == 0) h1[r * 512 + j] = fmaxf(acc + p1_b[j], 0.f);
}

// Stage 2: z = h1@p2_w.T + p2_b + sn, then LayerNorm -> sg. One block per row.
__global__ __launch_bounds__(256) void k_sup2(
    const float* __restrict__ sn, const float* __restrict__ h1,
    const float* __restrict__ p2_w, const float* __restrict__ p2_b,
    const float* __restrict__ ln_g, const float* __restrict__ ln_b,
    float* __restrict__ sg)
{
  const int r = blockIdx.x, t = threadIdx.x;
  const int lane = t & 63, wave = t >> 6;
  __shared__ float hs[512];
  __shared__ float zs[256];
  __shared__ float r1[4], r2[4];
  hs[t] = h1[r * 512 + t];
  hs[t + 256] = h1[r * 512 + 256 + t];
  __syncthreads();
  const int q = t & 3;
  #pragma unroll
  for (int jc = 0; jc < 4; ++jc) {
    int j = jc * 64 + (t >> 2);
    const float* wr = p2_w + (size_t)j * 512 + q * 128;
    float acc = 0.f;
    #pragma unroll
    for (int k = 0; k < 128; ++k) acc += hs[q * 128 + k] * wr[k];
    acc += __shfl_xor(acc, 1, 64);
    acc += __shfl_xor(acc, 2, 64);
    if (q == 0) zs[j] = acc + p2_b[j] + sn[r * 256 + j];
  }
  __syncthreads();
  float v = zs[t];
  float s1 = v, s2 = v * v;
  #pragma unroll
  for (int off = 32; off; off >>= 1) { s1 += __shfl_xor(s1, off, 64); s2 += __shfl_xor(s2, off, 64); }
  if (lane == 0) { r1[wave] = s1; r2[wave] = s2; }
  __syncthreads();
  float S1 = r1[0] + r1[1] + r1[2] + r1[3];
  float S2 = r2[0] + r2[1] + r2[2] + r2[3];
  float mu = S1 * (1.f / 256.f);
  float var = S2 * (1.f / 256.f) - mu * mu;
  sg[r * 256 + t] = (v - mu) * rsqrtf(var + 1e-6f) * ln_g[t] + ln_b[t];
}

// ---------------------------------------------------------------------------
// SG2[r][j] = sg[r] . w_hh[j][256:512] -> WWb[j][512+r] (bf16). Block 0 also
// writes sm[t] = mean_r sg[r][t].
__global__ __launch_bounds__(256) void k_sg2(
    const float* __restrict__ sg, const float* __restrict__ w_hh,
    bf16u* __restrict__ WWb, float* __restrict__ sm)
{
  __shared__ float s[5][256];
  const int t = threadIdx.x, lane = t & 63, wave = t >> 6;
  for (int i = t; i < 1280; i += 256) s[i >> 8][i & 255] = sg[i];
  __syncthreads();
  if (blockIdx.x == 0)
    sm[t] = (s[0][t] + s[1][t] + s[2][t] + s[3][t] + s[4][t]) * 0.2f;
  const int base = blockIdx.x * 256;
  for (int oi = wave; oi < 256; oi += 4) {
    int o = base + oi;                    // o = r*2048 + j
    int r = o >> 11, j = o & 2047;
    const float* wr = w_hh + (size_t)j * 512 + 256;
    float acc = 0.f;
    #pragma unroll
    for (int qq = 0; qq < 4; ++qq) acc += s[r][lane + 64*qq] * wr[lane + 64*qq];
    #pragma unroll
    for (int off = 32; off; off >>= 1) acc += __shfl_xor(acc, off, 64);
    if (lane == 0) WWb[(size_t)j * 576 + 512 + r] = f2b(acc);
  }
}

// ---------------------------------------------------------------------------
// gates[4096][2048] = XX[:, :K] @ WW[:, :K].T + bsum, bf16 MFMA 16x16x32.
__global__ __launch_bounds__(256) void k_gates_mfma(
    const bf16u* __restrict__ XX, const bf16u* __restrict__ WW,
    const float* __restrict__ bsum, float* __restrict__ gates, int kchunks)
{
  const int t = threadIdx.x;
  const int wave = t >> 6, lane = t & 63;
  const int quad = lane >> 4, l16 = lane & 15;
  const int wm = (wave >> 1) << 6, wn = (wave & 1) << 6;
  const int row0 = (blockIdx.x >> 4) << 7;
  const int col0 = (blockIdx.x & 15) << 7;
  __shared__ short As[128][40];
  __shared__ short Bs[128][40];
  f32x4 acc[4][4];
  #pragma unroll
  for (int i = 0; i < 4; ++i)
    #pragma unroll
    for (int j = 0; j < 4; ++j) acc[i][j] = (f32x4){0.f, 0.f, 0.f, 0.f};

  const int srow = t >> 1, shalf = t & 1;
  const bf16u* xp = XX + (size_t)(row0 + srow) * 576 + shalf * 16;
  const bf16u* wp = WW + (size_t)(col0 + srow) * 576 + shalf * 16;

  for (int kc = 0; kc < kchunks; ++kc) {
    uint4 x0 = *(const uint4*)(xp + kc * 32);
    uint4 x1 = *(const uint4*)(xp + kc * 32 + 8);
    uint4 w0 = *(const uint4*)(wp + kc * 32);
    uint4 w1 = *(const uint4*)(wp + kc * 32 + 8);
    __syncthreads();
    *(uint4*)&As[srow][shalf * 16] = x0;
    *(uint4*)&As[srow][shalf * 16 + 8] = x1;
    *(uint4*)&Bs[srow][shalf * 16] = w0;
    *(uint4*)&Bs[srow][shalf * 16 + 8] = w1;
    __syncthreads();
    bf16x8 af[4], bfr[4];
    #pragma unroll
    for (int i = 0; i < 4; ++i)
      af[i] = *(const bf16x8*)&As[wm + i * 16 + l16][quad * 8];
    #pragma unroll
    for (int j = 0; j < 4; ++j)
      bfr[j] = *(const bf16x8*)&Bs[wn + j * 16 + l16][quad * 8];
    #pragma unroll
    for (int i = 0; i < 4; ++i)
      #pragma unroll
      for (int j = 0; j < 4; ++j)
        acc[i][j] = __builtin_amdgcn_mfma_f32_16x16x32_bf16(af[i], bfr[j], acc[i][j], 0, 0, 0);
  }

  #pragma unroll
  for (int j = 0; j < 4; ++j) {
    const int col = col0 + wn + j * 16 + l16;
    const float bs = bsum[col];
    #pragma unroll
    for (int i = 0; i < 4; ++i) {
      #pragma unroll
      for (int r = 0; r < 4; ++r) {
        int row = row0 + wm + i * 16 + quad * 4 + r;
        gates[(size_t)row * 2048 + col] = acc[i][j][r] + bs;
      }
    }
  }
}

// ---------------------------------------------------------------------------
__device__ inline float block_sum256(float v, float* red) {
  const int lane = threadIdx.x & 63, wave = threadIdx.x >> 6;
  #pragma unroll
  for (int off = 32; off; off >>= 1) v += __shfl_xor(v, off, 64);
  if (lane == 0) red[wave] = v;
  __syncthreads();
  float r = red[0] + red[1] + red[2] + red[3];
  __syncthreads();
  return r;
}

// Cell pointwise + attention (writes bf16 hc/attn into XX) or final output.
__global__ __launch_bounds__(256) void k_cell(
    const float* __restrict__ gates, const float* __restrict__ qn,
    float* __restrict__ c, bf16u* __restrict__ XX,
    const float* __restrict__ sg, const float* __restrict__ sm,
    float* __restrict__ out, int step)
{
  __shared__ float red[4];
  const int b = blockIdx.x, t = threadIdx.x;
  const float* g = gates + (size_t)b * 2048;
  float i0 = g[t],        f0 = g[512 + t], gg0 = g[1024 + t], o0 = g[1536 + t];
  float i1 = g[256 + t],  f1 = g[768 + t], gg1 = g[1280 + t];
  float co0 = step ? c[b * 512 + t] : 0.f;
  float co1 = step ? c[b * 512 + 256 + t] : 0.f;
  float c0 = sigmoidf_(f0) * co0 + sigmoidf_(i0) * tanhf(gg0);
  float c1 = sigmoidf_(f1) * co1 + sigmoidf_(i1) * tanhf(gg1);
  c[b * 512 + t] = c0;
  c[b * 512 + 256 + t] = c1;
  float hcv = sigmoidf_(o0) * tanhf(c0);
  float h = qn[b * 256 + t] + hcv;
  if (step < 3) {
    XX[(size_t)b * 576 + 256 + t] = f2b(hcv);
    float dots[5];
    #pragma unroll
    for (int s = 0; s < 5; ++s) dots[s] = block_sum256(h * sg[s * 256 + t], red);
    float m = dots[0];
    #pragma unroll
    for (int s = 1; s < 5; ++s) m = fmaxf(m, dots[s]);
    float sum = 0.f;
    #pragma unroll
    for (int s = 0; s < 5; ++s) sum += __expf(dots[s] - m);
    if (t < 5) {
      float dv = (t == 1) ? dots[1] : (t == 2) ? dots[2] : (t == 3) ? dots[3]
               : (t == 4) ? dots[4] : dots[0];
      XX[(size_t)b * 576 + 512 + t] = f2b(__expf(dv - m) / sum);
    }
  } else {
    float tot = block_sum256(h * sm[t], red);
    if (t == 0) out[b] = tot;
  }
}

// ---------------------------------------------------------------------------
extern "C" void kernel_launch(void* const* d_in, const int* in_sizes, int n_in,
                              void* d_out, int out_size, void* d_ws, size_t ws_size,
                              hipStream_t stream)
{
  (void)in_sizes; (void)n_in; (void)out_size; (void)ws_size;
  const int *q_l1 = (const int*)d_in[0], *q_l2 = (const int*)d_in[1];
  const int *q_r1 = (const int*)d_in[2], *q_r2 = (const int*)d_in[3];
  const int *s_l1 = (const int*)d_in[4], *s_l2 = (const int*)d_in[5];
  const int *s_r1 = (const int*)d_in[6], *s_r2 = (const int*)d_in[7];
  const float* emb      = (const float*)d_in[12];
  const float* gcn_w    = (const float*)d_in[13];
  const float* gcn_wb   = (const float*)d_in[14];
  const float* gcn_b    = (const float*)d_in[15];
  const float* hop_gate = (const float*)d_in[16];
  const float* attn_w   = (const float*)d_in[17];
  const float* p1_w = (const float*)d_in[19];
  const float* p1_b = (const float*)d_in[20];
  const float* p2_w = (const float*)d_in[21];
  const float* p2_b = (const float*)d_in[22];
  const float* ln_g = (const float*)d_in[23];
  const float* ln_b = (const float*)d_in[24];
  const float* w_ih = (const float*)d_in[25];
  const float* w_hh = (const float*)d_in[26];
  const float* b_ih = (const float*)d_in[27];
  const float* b_hh = (const float*)d_in[28];

  char* base = (char*)d_ws;
  size_t off = 0;
  auto alloc = [&](size_t bytes) -> char* {
    char* r = base + off;
    off = (off + bytes + 255) & ~(size_t)255;
    return r;
  };
  bf16u* pr    = (bf16u*)alloc(100001ull * 128 * 2);
  bf16u* pe    = (bf16u*)alloc(100001ull * 128 * 2);
  float* srel  = (float*)alloc(100001ull * 4);
  float* sent  = (float*)alloc(100001ull * 4);
  float* uvec  = (float*)alloc(256 * 4);
  bf16u* Vp    = (bf16u*)alloc(256 * 128 * 2);
  float* qn    = (float*)alloc(4096ull * 256 * 4);
  float* sn    = (float*)alloc(5 * 256 * 4);
  float* sg    = (float*)alloc(5 * 256 * 4);
  float* sm    = (float*)alloc(256 * 4);
  float* h1b   = (float*)alloc(5 * 512 * 4);
  bf16u* XX    = (bf16u*)alloc(4096ull * 576 * 2);
  bf16u* WWa   = (bf16u*)alloc(2048ull * 576 * 2);
  bf16u* WWb   = (bf16u*)alloc(2048ull * 576 * 2);
  float* bsum  = (float*)alloc(2048 * 4);
  float* gates = (float*)alloc(4096ull * 2048 * 4);
  float* cbuf  = (float*)alloc(4096ull * 512 * 4);

  k_vconv<<<256, 128, 0, stream>>>(gcn_w, Vp);
  k_uvec<<<1, 256, 0, stream>>>(gcn_w, attn_w, uvec);
  k_pre_gemm<<<782, 256, 0, stream>>>(emb, Vp, uvec, pr, pe, srel, sent);
  k_weights<<<2048, 256, 0, stream>>>(w_ih, w_hh, b_ih, b_hh, WWa, WWb, bsum);
  k_init<<<4096, 64, 0, stream>>>(XX);
  k_neighbor<<<4096, 256, 0, stream>>>(q_l1, q_l2, pr, pe, srel, sent, gcn_wb, gcn_b, hop_gate, qn, XX, 0);
  k_neighbor<<<4096, 256, 0, stream>>>(q_r1, q_r2, pr, pe, srel, sent, gcn_wb, gcn_b, hop_gate, qn, XX, 128);
  k_neighbor<<<5, 256, 0, stream>>>(s_l1, s_l2, pr, pe, srel, sent, gcn_wb, gcn_b, hop_gate, sn, (bf16u*)nullptr, 0);
  k_neighbor<<<5, 256, 0, stream>>>(s_r1, s_r2, pr, pe, srel, sent, gcn_wb, gcn_b, hop_gate, sn, (bf16u*)nullptr, 128);
  k_sup1<<<40, 256, 0, stream>>>(sn, p1_w, p1_b, h1b);
  k_sup2<<<5, 256, 0, stream>>>(sn, h1b, p2_w, p2_b, ln_g, ln_b, sg);
  k_sg2<<<40, 256, 0, stream>>>(sg, w_hh, WWb, sm);

  for (int step = 0; step < 4; ++step) {
    if (step == 0)
      k_gates_mfma<<<512, 256, 0, stream>>>(XX, WWa, bsum, gates, 8);
    else
      k_gates_mfma<<<512, 256, 0, stream>>>(XX, WWb, bsum, gates, 17);
    k_cell<<<4096, 256, 0, stream>>>(gates, qn, cbuf, XX, sg, sm, (float*)d_out, step);
  }
}

// Round 6
// 465.586 us; speedup vs baseline: 3.5606x; 1.0942x over previous
//
#include <hip/hip_runtime.h>

typedef unsigned short bf16u;
typedef unsigned int u32;
typedef float f32x4 __attribute__((ext_vector_type(4)));
typedef short bf16x8 __attribute__((ext_vector_type(8)));

__device__ inline float sigmoidf_(float x) { return 1.f / (1.f + __expf(-x)); }
__device__ inline float b2f(bf16u u) { return __uint_as_float(((u32)u) << 16); }
__device__ inline float blo(u32 u) { return __uint_as_float(u << 16); }
__device__ inline float bhi(u32 u) { return __uint_as_float(u & 0xffff0000u); }
__device__ inline bf16u f2b(float f) {
  u32 i = __float_as_uint(f);
  u32 r = (i + 0x7fffu + ((i >> 16) & 1u)) >> 16;
  return (bf16u)r;
}

// ---------------------------------------------------------------------------
// Vp[o][k] = bf16(gcn_w[o&127][(o>>7)*128 + k]), o in [0,256), k in [0,128)
__global__ __launch_bounds__(128) void k_vconv(
    const float* __restrict__ gcn_w, bf16u* __restrict__ Vp)
{
  const int o = blockIdx.x, k = threadIdx.x;
  Vp[o * 128 + k] = f2b(gcn_w[(o & 127) * 256 + ((o >> 7) << 7) + k]);
}

// uvec[o] = sum_d gcn_w[d][(o>>7)*128 + (o&127)] * attn_w[d]   (one block)
__global__ __launch_bounds__(256) void k_uvec(
    const float* __restrict__ gcn_w, const float* __restrict__ attn_w,
    float* __restrict__ uvec)
{
  const int o = threadIdx.x;
  const int col = ((o >> 7) << 7) + (o & 127);
  float acc = 0.f;
  for (int d = 0; d < 128; ++d) acc += gcn_w[d * 256 + col] * attn_w[d];
  uvec[o] = acc;
}

// ---------------------------------------------------------------------------
// pr/pe tables via bf16 MFMA + fused fp32 score GEMV.
// Block: 64 emb rows, K=128. B (128 cols) staged per half; LDS ~53 KB ->
// 3 blocks/CU. acc = 8 f32x4/lane.
__global__ __launch_bounds__(256) void k_pre_gemm(
    const float* __restrict__ emb, const bf16u* __restrict__ Vp,
    const float* __restrict__ uvec,
    bf16u* __restrict__ pr, bf16u* __restrict__ pe,
    float* __restrict__ srel, float* __restrict__ sent)
{
  const int t = threadIdx.x;
  const int row0 = blockIdx.x << 6;
  __shared__ short As[64][136];
  __shared__ short Bs[128][136];
  __shared__ float us[256];
  us[t] = uvec[t];
  // stage B half 0 (pr cols): Vp rows 0..127, 16 uint4/row
  {
    const uint4* src = (const uint4*)Vp;
    #pragma unroll
    for (int s = 0; s < 8; ++s) {
      int f = s * 256 + t;
      *(uint4*)&Bs[f >> 4][(f & 15) * 8] = src[f];
    }
  }
  __syncthreads();                 // us (and Bs ordering) visible
  // stage A (fp32 -> bf16) + fused scores
  #pragma unroll
  for (int s = 0; s < 8; ++s) {
    int f = s * 256 + t;           // float4 idx: 64 rows x 32
    int row = f >> 5, q = f & 31;
    int gr = row0 + row; if (gr > 100000) gr = 100000;
    float4 v = *(const float4*)&emb[(size_t)gr * 128 + (q << 2)];
    ushort4 pk;
    pk.x = f2b(v.x); pk.y = f2b(v.y); pk.z = f2b(v.z); pk.w = f2b(v.w);
    *(ushort4*)&As[row][q << 2] = pk;
    float p0 = v.x * us[4*q+0] + v.y * us[4*q+1] + v.z * us[4*q+2] + v.w * us[4*q+3];
    float p1 = v.x * us[128+4*q+0] + v.y * us[128+4*q+1] + v.z * us[128+4*q+2] + v.w * us[128+4*q+3];
    #pragma unroll
    for (int off = 16; off; off >>= 1) {
      p0 += __shfl_xor(p0, off, 64);
      p1 += __shfl_xor(p1, off, 64);
    }
    if ((t & 31) == 0) { srel[gr] = p0; sent[gr] = p1; }
  }
  __syncthreads();
  const int wave = t >> 6, lane = t & 63;
  const int quad = lane >> 4, l16 = lane & 15;
  const int wm = (wave >> 1) << 5, wn = (wave & 1) << 6;
  #pragma unroll
  for (int half = 0; half < 2; ++half) {
    f32x4 acc[2][4];
    #pragma unroll
    for (int i = 0; i < 2; ++i)
      #pragma unroll
      for (int j = 0; j < 4; ++j) acc[i][j] = (f32x4){0.f, 0.f, 0.f, 0.f};
    #pragma unroll
    for (int kc = 0; kc < 4; ++kc) {
      bf16x8 af[2], bfr[4];
      #pragma unroll
      for (int i = 0; i < 2; ++i)
        af[i] = *(const bf16x8*)&As[wm + i * 16 + l16][kc * 32 + quad * 8];
      #pragma unroll
      for (int j = 0; j < 4; ++j)
        bfr[j] = *(const bf16x8*)&Bs[wn + j * 16 + l16][kc * 32 + quad * 8];
      #pragma unroll
      for (int i = 0; i < 2; ++i)
        #pragma unroll
        for (int j = 0; j < 4; ++j)
          acc[i][j] = __builtin_amdgcn_mfma_f32_16x16x32_bf16(af[i], bfr[j], acc[i][j], 0, 0, 0);
    }
    bf16u* tab = half ? pe : pr;
    #pragma unroll
    for (int j = 0; j < 4; ++j) {
      const int col = wn + j * 16 + l16;
      #pragma unroll
      for (int i = 0; i < 2; ++i) {
        #pragma unroll
        for (int r = 0; r < 4; ++r) {
          int row = row0 + wm + i * 16 + quad * 4 + r;
          if (row <= 100000) tab[(size_t)row * 128 + col] = f2b(acc[i][j][r]);
        }
      }
    }
    if (half == 0) {
      __syncthreads();             // all waves done reading Bs half 0
      const uint4* src = (const uint4*)(Vp + 128 * 128);
      #pragma unroll
      for (int s = 0; s < 8; ++s) {
        int f = s * 256 + t;
        *(uint4*)&Bs[f >> 4][(f & 15) * 8] = src[f];
      }
      __syncthreads();
    }
  }
}

// ---------------------------------------------------------------------------
// Weight prep (bf16 packed): WWa[j][0:256]=w_ih; WWb[j][0:256]=w_ih+whh1,
// [256:512]=whh1, [517:544]=0. bsum = b_ih + b_hh (fp32).
__global__ __launch_bounds__(256) void k_weights(
    const float* __restrict__ w_ih, const float* __restrict__ w_hh,
    const float* __restrict__ b_ih, const float* __restrict__ b_hh,
    bf16u* __restrict__ WWa, bf16u* __restrict__ WWb, float* __restrict__ bsum)
{
  const int j = blockIdx.x, k = threadIdx.x;
  float wi = w_ih[j * 256 + k];
  float wh = w_hh[j * 512 + k];
  WWa[(size_t)j * 576 + k] = f2b(wi);
  WWb[(size_t)j * 576 + k] = f2b(wi + wh);
  WWb[(size_t)j * 576 + 256 + k] = f2b(wh);
  if (k < 27) WWb[(size_t)j * 576 + 517 + k] = 0;
  if (k == 0) bsum[j] = b_ih[j] + b_hh[j];
}

// Zero XX pad cols 517..543.
__global__ __launch_bounds__(64) void k_init(bf16u* __restrict__ XX)
{
  if (threadIdx.x < 27) XX[(size_t)blockIdx.x * 576 + 517 + threadIdx.x] = 0;
}

// ---------------------------------------------------------------------------
// Neighbor pair encoder v3: 16B gathers (16 lanes/row, 8 k-groups).
__global__ __launch_bounds__(256) void k_neighbor(
    const int* __restrict__ connA, const int* __restrict__ connB,
    const bf16u* __restrict__ pr, const bf16u* __restrict__ pe,
    const float* __restrict__ srel, const float* __restrict__ sent,
    const float* __restrict__ gcn_wb, const float* __restrict__ gcn_b,
    const float* __restrict__ hop_gate,
    float* __restrict__ out, bf16u* __restrict__ xx, int coloff)
{
  const int n = blockIdx.x, t = threadIdx.x;
  __shared__ int idxA[64][2], idxB[64][2];
  __shared__ float wA[64], wB[64];
  __shared__ float red[2][8][16][8];   // hop, kgroup, p, comp
  if (t < 128) {
    const int hop = t >> 6, nn = t & 63;
    const int* conn = hop ? connB : connA;
    int rel = conn[(n * 64 + nn) * 2 + 0];
    int ent = conn[(n * 64 + nn) * 2 + 1];
    int (*idx)[2] = hop ? idxB : idxA;
    idx[nn][0] = rel; idx[nn][1] = ent;
    float sc = srel[rel] + sent[ent];
    float m = sc;
    #pragma unroll
    for (int off = 32; off; off >>= 1) m = fmaxf(m, __shfl_xor(m, off, 64));
    float e = __expf(sc - m);
    float s = e;
    #pragma unroll
    for (int off = 32; off; off >>= 1) s += __shfl_xor(s, off, 64);
    (hop ? wB : wA)[nn] = e / s;
  }
  __syncthreads();
  {
    const int hop = t >> 7, g = (t >> 4) & 7, p = t & 15;
    const int (*idx)[2] = hop ? idxB : idxA;
    const float* w = hop ? wB : wA;
    float a[8];
    #pragma unroll
    for (int c = 0; c < 8; ++c) a[c] = 0.f;
    #pragma unroll
    for (int kk = 0; kk < 8; ++kk) {
      int k = g + (kk << 3);
      float wk = w[k];
      uint4 ra = *(const uint4*)&pr[(size_t)idx[k][0] * 128 + p * 8];
      uint4 rb = *(const uint4*)&pe[(size_t)idx[k][1] * 128 + p * 8];
      a[0] += wk * (blo(ra.x) + blo(rb.x)); a[1] += wk * (bhi(ra.x) + bhi(rb.x));
      a[2] += wk * (blo(ra.y) + blo(rb.y)); a[3] += wk * (bhi(ra.y) + bhi(rb.y));
      a[4] += wk * (blo(ra.z) + blo(rb.z)); a[5] += wk * (bhi(ra.z) + bhi(rb.z));
      a[6] += wk * (blo(ra.w) + blo(rb.w)); a[7] += wk * (bhi(ra.w) + bhi(rb.w));
    }
    *(float4*)&red[hop][g][p][0] = (float4){a[0], a[1], a[2], a[3]};
    *(float4*)&red[hop][g][p][4] = (float4){a[4], a[5], a[6], a[7]};
  }
  __syncthreads();
  if (t < 128) {
    const int d = t, p = d >> 3, cq = d & 7;
    float accA = 0.f, accB = 0.f;
    #pragma unroll
    for (int g = 0; g < 8; ++g) {
      accA += red[0][g][p][cq];
      accB += red[1][g][p][cq];
    }
    float bias = gcn_wb[d] + gcn_b[d];
    float g0 = hop_gate[0], g1 = hop_gate[1];
    float mx = fmaxf(g0, g1);
    float e0 = __expf(g0 - mx), e1 = __expf(g1 - mx);
    float inv = 1.f / (e0 + e1);
    float v = e0 * inv * tanhf(bias + accA) + e1 * inv * tanhf(bias + accB);
    out[n * 256 + coloff + d] = v;
    if (xx) xx[(size_t)n * 576 + coloff + d] = f2b(v);
  }
}

// ---------------------------------------------------------------------------
// Support encoder stage 1: h1[r][j] = relu(sn[r] . p1_w[j] + p1_b[j]).
__global__ __launch_bounds__(256) void k_sup1(
    const float* __restrict__ sn, const float* __restrict__ p1_w,
    const float* __restrict__ p1_b, float* __restrict__ h1)
{
  const int r = blockIdx.x >> 3, j0 = (blockIdx.x & 7) << 6;
  const int t = threadIdx.x;
  __shared__ float xs[256];
  xs[t] = sn[r * 256 + t];
  __syncthreads();
  const int j = j0 + (t >> 2), q = t & 3;
  const float* wr = p1_w + (size_t)j * 256 + q * 64;
  float acc = 0.f;
  #pragma unroll
  for (int k = 0; k < 64; ++k) acc += xs[q * 64 + k] * wr[k];
  acc += __shfl_xor(acc, 1, 64);
  acc += __shfl_xor(acc, 2, 64);
  if (q == 0) h1[r * 512 + j] = fmaxf(acc + p1_b[j], 0.f);
}

// Stage 2: z = h1@p2_w.T + p2_b + sn, then LayerNorm -> sg. One block per row.
__global__ __launch_bounds__(256) void k_sup2(
    const float* __restrict__ sn, const float* __restrict__ h1,
    const float* __restrict__ p2_w, const float* __restrict__ p2_b,
    const float* __restrict__ ln_g, const float* __restrict__ ln_b,
    float* __restrict__ sg)
{
  const int r = blockIdx.x, t = threadIdx.x;
  const int lane = t & 63, wave = t >> 6;
  __shared__ float hs[512];
  __shared__ float zs[256];
  __shared__ float r1[4], r2[4];
  hs[t] = h1[r * 512 + t];
  hs[t + 256] = h1[r * 512 + 256 + t];
  __syncthreads();
  const int q = t & 3;
  #pragma unroll
  for (int jc = 0; jc < 4; ++jc) {
    int j = jc * 64 + (t >> 2);
    const float* wr = p2_w + (size_t)j * 512 + q * 128;
    float acc = 0.f;
    #pragma unroll
    for (int k = 0; k < 128; ++k) acc += hs[q * 128 + k] * wr[k];
    acc += __shfl_xor(acc, 1, 64);
    acc += __shfl_xor(acc, 2, 64);
    if (q == 0) zs[j] = acc + p2_b[j] + sn[r * 256 + j];
  }
  __syncthreads();
  float v = zs[t];
  float s1 = v, s2 = v * v;
  #pragma unroll
  for (int off = 32; off; off >>= 1) { s1 += __shfl_xor(s1, off, 64); s2 += __shfl_xor(s2, off, 64); }
  if (lane == 0) { r1[wave] = s1; r2[wave] = s2; }
  __syncthreads();
  float S1 = r1[0] + r1[1] + r1[2] + r1[3];
  float S2 = r2[0] + r2[1] + r2[2] + r2[3];
  float mu = S1 * (1.f / 256.f);
  float var = S2 * (1.f / 256.f) - mu * mu;
  sg[r * 256 + t] = (v - mu) * rsqrtf(var + 1e-6f) * ln_g[t] + ln_b[t];
}

// ---------------------------------------------------------------------------
// SG2[r][j] = sg[r] . w_hh[j][256:512] -> WWb[j][512+r] (bf16). Block 0 also
// writes sm[t] = mean_r sg[r][t].
__global__ __launch_bounds__(256) void k_sg2(
    const float* __restrict__ sg, const float* __restrict__ w_hh,
    bf16u* __restrict__ WWb, float* __restrict__ sm)
{
  __shared__ float s[5][256];
  const int t = threadIdx.x, lane = t & 63, wave = t >> 6;
  for (int i = t; i < 1280; i += 256) s[i >> 8][i & 255] = sg[i];
  __syncthreads();
  if (blockIdx.x == 0)
    sm[t] = (s[0][t] + s[1][t] + s[2][t] + s[3][t] + s[4][t]) * 0.2f;
  const int base = blockIdx.x * 256;
  for (int oi = wave; oi < 256; oi += 4) {
    int o = base + oi;                    // o = r*2048 + j
    int r = o >> 11, j = o & 2047;
    const float* wr = w_hh + (size_t)j * 512 + 256;
    float acc = 0.f;
    #pragma unroll
    for (int qq = 0; qq < 4; ++qq) acc += s[r][lane + 64*qq] * wr[lane + 64*qq];
    #pragma unroll
    for (int off = 32; off; off >>= 1) acc += __shfl_xor(acc, off, 64);
    if (lane == 0) WWb[(size_t)j * 576 + 512 + r] = f2b(acc);
  }
}

// ---------------------------------------------------------------------------
// gates[4096][2048] = XX[:, :K] @ WW[:, :K].T + bsum, bf16 MFMA 16x16x32.
// Software-prefetch of the next K-chunk before the MFMA block.
__global__ __launch_bounds__(256) void k_gates_mfma(
    const bf16u* __restrict__ XX, const bf16u* __restrict__ WW,
    const float* __restrict__ bsum, float* __restrict__ gates, int kchunks)
{
  const int t = threadIdx.x;
  const int wave = t >> 6, lane = t & 63;
  const int quad = lane >> 4, l16 = lane & 15;
  const int wm = (wave >> 1) << 6, wn = (wave & 1) << 6;
  const int row0 = (blockIdx.x >> 4) << 7;
  const int col0 = (blockIdx.x & 15) << 7;
  __shared__ short As[128][40];
  __shared__ short Bs[128][40];
  f32x4 acc[4][4];
  #pragma unroll
  for (int i = 0; i < 4; ++i)
    #pragma unroll
    for (int j = 0; j < 4; ++j) acc[i][j] = (f32x4){0.f, 0.f, 0.f, 0.f};

  const int srow = t >> 1, shalf = t & 1;
  const bf16u* xp = XX + (size_t)(row0 + srow) * 576 + shalf * 16;
  const bf16u* wp = WW + (size_t)(col0 + srow) * 576 + shalf * 16;

  uint4 x0 = *(const uint4*)(xp);
  uint4 x1 = *(const uint4*)(xp + 8);
  uint4 w0 = *(const uint4*)(wp);
  uint4 w1 = *(const uint4*)(wp + 8);

  for (int kc = 0; kc < kchunks; ++kc) {
    __syncthreads();
    *(uint4*)&As[srow][shalf * 16] = x0;
    *(uint4*)&As[srow][shalf * 16 + 8] = x1;
    *(uint4*)&Bs[srow][shalf * 16] = w0;
    *(uint4*)&Bs[srow][shalf * 16 + 8] = w1;
    __syncthreads();
    if (kc + 1 < kchunks) {
      x0 = *(const uint4*)(xp + (kc+1) * 32);
      x1 = *(const uint4*)(xp + (kc+1) * 32 + 8);
      w0 = *(const uint4*)(wp + (kc+1) * 32);
      w1 = *(const uint4*)(wp + (kc+1) * 32 + 8);
    }
    bf16x8 af[4], bfr[4];
    #pragma unroll
    for (int i = 0; i < 4; ++i)
      af[i] = *(const bf16x8*)&As[wm + i * 16 + l16][quad * 8];
    #pragma unroll
    for (int j = 0; j < 4; ++j)
      bfr[j] = *(const bf16x8*)&Bs[wn + j * 16 + l16][quad * 8];
    #pragma unroll
    for (int i = 0; i < 4; ++i)
      #pragma unroll
      for (int j = 0; j < 4; ++j)
        acc[i][j] = __builtin_amdgcn_mfma_f32_16x16x32_bf16(af[i], bfr[j], acc[i][j], 0, 0, 0);
  }

  #pragma unroll
  for (int j = 0; j < 4; ++j) {
    const int col = col0 + wn + j * 16 + l16;
    const float bs = bsum[col];
    #pragma unroll
    for (int i = 0; i < 4; ++i) {
      #pragma unroll
      for (int r = 0; r < 4; ++r) {
        int row = row0 + wm + i * 16 + quad * 4 + r;
        gates[(size_t)row * 2048 + col] = acc[i][j][r] + bs;
      }
    }
  }
}

// ---------------------------------------------------------------------------
__device__ inline float block_sum256(float v, float* red) {
  const int lane = threadIdx.x & 63, wave = threadIdx.x >> 6;
  #pragma unroll
  for (int off = 32; off; off >>= 1) v += __shfl_xor(v, off, 64);
  if (lane == 0) red[wave] = v;
  __syncthreads();
  float r = red[0] + red[1] + red[2] + red[3];
  __syncthreads();
  return r;
}

// Cell pointwise + attention (writes bf16 hc/attn into XX) or final output.
__global__ __launch_bounds__(256) void k_cell(
    const float* __restrict__ gates, const float* __restrict__ qn,
    float* __restrict__ c, bf16u* __restrict__ XX,
    const float* __restrict__ sg, const float* __restrict__ sm,
    float* __restrict__ out, int step)
{
  __shared__ float red[4];
  const int b = blockIdx.x, t = threadIdx.x;
  const float* g = gates + (size_t)b * 2048;
  float i0 = g[t],        f0 = g[512 + t], gg0 = g[1024 + t], o0 = g[1536 + t];
  float i1 = g[256 + t],  f1 = g[768 + t], gg1 = g[1280 + t];
  float co0 = step ? c[b * 512 + t] : 0.f;
  float co1 = step ? c[b * 512 + 256 + t] : 0.f;
  float c0 = sigmoidf_(f0) * co0 + sigmoidf_(i0) * tanhf(gg0);
  float c1 = sigmoidf_(f1) * co1 + sigmoidf_(i1) * tanhf(gg1);
  c[b * 512 + t] = c0;
  c[b * 512 + 256 + t] = c1;
  float hcv = sigmoidf_(o0) * tanhf(c0);
  float h = qn[b * 256 + t] + hcv;
  if (step < 3) {
    XX[(size_t)b * 576 + 256 + t] = f2b(hcv);
    float dots[5];
    #pragma unroll
    for (int s = 0; s < 5; ++s) dots[s] = block_sum256(h * sg[s * 256 + t], red);
    float m = dots[0];
    #pragma unroll
    for (int s = 1; s < 5; ++s) m = fmaxf(m, dots[s]);
    float sum = 0.f;
    #pragma unroll
    for (int s = 0; s < 5; ++s) sum += __expf(dots[s] - m);
    if (t < 5) {
      float dv = (t == 1) ? dots[1] : (t == 2) ? dots[2] : (t == 3) ? dots[3]
               : (t == 4) ? dots[4] : dots[0];
      XX[(size_t)b * 576 + 512 + t] = f2b(__expf(dv - m) / sum);
    }
  } else {
    float tot = block_sum256(h * sm[t], red);
    if (t == 0) out[b] = tot;
  }
}

// ---------------------------------------------------------------------------
extern "C" void kernel_launch(void* const* d_in, const int* in_sizes, int n_in,
                              void* d_out, int out_size, void* d_ws, size_t ws_size,
                              hipStream_t stream)
{
  (void)in_sizes; (void)n_in; (void)out_size; (void)ws_size;
  const int *q_l1 = (const int*)d_in[0], *q_l2 = (const int*)d_in[1];
  const int *q_r1 = (const int*)d_in[2], *q_r2 = (const int*)d_in[3];
  const int *s_l1 = (const int*)d_in[4], *s_l2 = (const int*)d_in[5];
  const int *s_r1 = (const int*)d_in[6], *s_r2 = (const int*)d_in[7];
  const float* emb      = (const float*)d_in[12];
  const float* gcn_w    = (const float*)d_in[13];
  const float* gcn_wb   = (const float*)d_in[14];
  const float* gcn_b    = (const float*)d_in[15];
  const float* hop_gate = (const float*)d_in[16];
  const float* attn_w   = (const float*)d_in[17];
  const float* p1_w = (const float*)d_in[19];
  const float* p1_b = (const float*)d_in[20];
  const float* p2_w = (const float*)d_in[21];
  const float* p2_b = (const float*)d_in[22];
  const float* ln_g = (const float*)d_in[23];
  const float* ln_b = (const float*)d_in[24];
  const float* w_ih = (const float*)d_in[25];
  const float* w_hh = (const float*)d_in[26];
  const float* b_ih = (const float*)d_in[27];
  const float* b_hh = (const float*)d_in[28];

  char* base = (char*)d_ws;
  size_t off = 0;
  auto alloc = [&](size_t bytes) -> char* {
    char* r = base + off;
    off = (off + bytes + 255) & ~(size_t)255;
    return r;
  };
  bf16u* pr    = (bf16u*)alloc(100001ull * 128 * 2);
  bf16u* pe    = (bf16u*)alloc(100001ull * 128 * 2);
  float* srel  = (float*)alloc(100001ull * 4);
  float* sent  = (float*)alloc(100001ull * 4);
  float* uvec  = (float*)alloc(256 * 4);
  bf16u* Vp    = (bf16u*)alloc(256 * 128 * 2);
  float* qn    = (float*)alloc(4096ull * 256 * 4);
  float* sn    = (float*)alloc(5 * 256 * 4);
  float* sg    = (float*)alloc(5 * 256 * 4);
  float* sm    = (float*)alloc(256 * 4);
  float* h1b   = (float*)alloc(5 * 512 * 4);
  bf16u* XX    = (bf16u*)alloc(4096ull * 576 * 2);
  bf16u* WWa   = (bf16u*)alloc(2048ull * 576 * 2);
  bf16u* WWb   = (bf16u*)alloc(2048ull * 576 * 2);
  float* bsum  = (float*)alloc(2048 * 4);
  float* gates = (float*)alloc(4096ull * 2048 * 4);
  float* cbuf  = (float*)alloc(4096ull * 512 * 4);

  k_vconv<<<256, 128, 0, stream>>>(gcn_w, Vp);
  k_uvec<<<1, 256, 0, stream>>>(gcn_w, attn_w, uvec);
  k_pre_gemm<<<1563, 256, 0, stream>>>(emb, Vp, uvec, pr, pe, srel, sent);
  k_weights<<<2048, 256, 0, stream>>>(w_ih, w_hh, b_ih, b_hh, WWa, WWb, bsum);
  k_init<<<4096, 64, 0, stream>>>(XX);
  k_neighbor<<<4096, 256, 0, stream>>>(q_l1, q_l2, pr, pe, srel, sent, gcn_wb, gcn_b, hop_gate, qn, XX, 0);
  k_neighbor<<<4096, 256, 0, stream>>>(q_r1, q_r2, pr, pe, srel, sent, gcn_wb, gcn_b, hop_gate, qn, XX, 128);
  k_neighbor<<<5, 256, 0, stream>>>(s_l1, s_l2, pr, pe, srel, sent, gcn_wb, gcn_b, hop_gate, sn, (bf16u*)nullptr, 0);
  k_neighbor<<<5, 256, 0, stream>>>(s_r1, s_r2, pr, pe, srel, sent, gcn_wb, gcn_b, hop_gate, sn, (bf16u*)nullptr, 128);
  k_sup1<<<40, 256, 0, stream>>>(sn, p1_w, p1_b, h1b);
  k_sup2<<<5, 256, 0, stream>>>(sn, h1b, p2_w, p2_b, ln_g, ln_b, sg);
  k_sg2<<<40, 256, 0, stream>>>(sg, w_hh, WWb, sm);

  for (int step = 0; step < 4; ++step) {
    if (step == 0)
      k_gates_mfma<<<512, 256, 0, stream>>>(XX, WWa, bsum, gates, 8);
    else
      k_gates_mfma<<<512, 256, 0, stream>>>(XX, WWb, bsum, gates, 17);
    k_cell<<<4096, 256, 0, stream>>>(gates, qn, cbuf, XX, sg, sm, (float*)d_out, step);
  }
}

// Round 7
// 396.280 us; speedup vs baseline: 4.1833x; 1.1749x over previous
//
#include <hip/hip_runtime.h>

typedef unsigned short bf16u;
typedef unsigned int u32;
typedef float f32x4 __attribute__((ext_vector_type(4)));
typedef short bf16x8 __attribute__((ext_vector_type(8)));

__device__ inline float sigmoidf_(float x) { return 1.f / (1.f + __expf(-x)); }
__device__ inline float b2f(bf16u u) { return __uint_as_float(((u32)u) << 16); }
__device__ inline float blo(u32 u) { return __uint_as_float(u << 16); }
__device__ inline float bhi(u32 u) { return __uint_as_float(u & 0xffff0000u); }
__device__ inline bf16u f2b(float f) {
  u32 i = __float_as_uint(f);
  u32 r = (i + 0x7fffu + ((i >> 16) & 1u)) >> 16;
  return (bf16u)r;
}

// ---------------------------------------------------------------------------
// Fused prep: XX pad zero (all 4096 blocks), LSTM weight pack (b<2048),
// Vp bf16 conversion (b in [2048,2304)), uvec (b==2304).
__global__ __launch_bounds__(256) void k_prep(
    const float* __restrict__ gcn_w, const float* __restrict__ attn_w,
    const float* __restrict__ w_ih, const float* __restrict__ w_hh,
    const float* __restrict__ b_ih, const float* __restrict__ b_hh,
    bf16u* __restrict__ Vp, float* __restrict__ uvec,
    bf16u* __restrict__ WWa, bf16u* __restrict__ WWb, float* __restrict__ bsum,
    bf16u* __restrict__ XX)
{
  const int b = blockIdx.x, t = threadIdx.x;
  if (t < 27) XX[(size_t)b * 576 + 517 + t] = 0;
  if (b < 2048) {
    float wi = w_ih[b * 256 + t];
    float wh = w_hh[b * 512 + t];
    WWa[(size_t)b * 576 + t] = f2b(wi);
    WWb[(size_t)b * 576 + t] = f2b(wi + wh);
    WWb[(size_t)b * 576 + 256 + t] = f2b(wh);
    if (t < 27) WWb[(size_t)b * 576 + 517 + t] = 0;
    if (t == 0) bsum[b] = b_ih[b] + b_hh[b];
  } else if (b < 2304) {
    const int o = b - 2048;
    if (t < 128) Vp[o * 128 + t] = f2b(gcn_w[(o & 127) * 256 + ((o >> 7) << 7) + t]);
  } else if (b == 2304) {
    const int col = ((t >> 7) << 7) + (t & 127);
    float acc = 0.f;
    for (int d = 0; d < 128; ++d) acc += gcn_w[d * 256 + col] * attn_w[d];
    uvec[t] = acc;
  }
}

// ---------------------------------------------------------------------------
// pr/pe tables via bf16 MFMA + fused fp32 score GEMV. 64-row panels.
__global__ __launch_bounds__(256) void k_pre_gemm(
    const float* __restrict__ emb, const bf16u* __restrict__ Vp,
    const float* __restrict__ uvec,
    bf16u* __restrict__ pr, bf16u* __restrict__ pe,
    float* __restrict__ srel, float* __restrict__ sent)
{
  const int t = threadIdx.x;
  const int row0 = blockIdx.x << 6;
  __shared__ short As[64][136];
  __shared__ short Bs[128][136];
  __shared__ float us[256];
  us[t] = uvec[t];
  {
    const uint4* src = (const uint4*)Vp;
    #pragma unroll
    for (int s = 0; s < 8; ++s) {
      int f = s * 256 + t;
      *(uint4*)&Bs[f >> 4][(f & 15) * 8] = src[f];
    }
  }
  __syncthreads();
  #pragma unroll
  for (int s = 0; s < 8; ++s) {
    int f = s * 256 + t;
    int row = f >> 5, q = f & 31;
    int gr = row0 + row; if (gr > 100000) gr = 100000;
    float4 v = *(const float4*)&emb[(size_t)gr * 128 + (q << 2)];
    ushort4 pk;
    pk.x = f2b(v.x); pk.y = f2b(v.y); pk.z = f2b(v.z); pk.w = f2b(v.w);
    *(ushort4*)&As[row][q << 2] = pk;
    float p0 = v.x * us[4*q+0] + v.y * us[4*q+1] + v.z * us[4*q+2] + v.w * us[4*q+3];
    float p1 = v.x * us[128+4*q+0] + v.y * us[128+4*q+1] + v.z * us[128+4*q+2] + v.w * us[128+4*q+3];
    #pragma unroll
    for (int off = 16; off; off >>= 1) {
      p0 += __shfl_xor(p0, off, 64);
      p1 += __shfl_xor(p1, off, 64);
    }
    if ((t & 31) == 0) { srel[gr] = p0; sent[gr] = p1; }
  }
  __syncthreads();
  const int wave = t >> 6, lane = t & 63;
  const int quad = lane >> 4, l16 = lane & 15;
  const int wm = (wave >> 1) << 5, wn = (wave & 1) << 6;
  #pragma unroll
  for (int half = 0; half < 2; ++half) {
    f32x4 acc[2][4];
    #pragma unroll
    for (int i = 0; i < 2; ++i)
      #pragma unroll
      for (int j = 0; j < 4; ++j) acc[i][j] = (f32x4){0.f, 0.f, 0.f, 0.f};
    #pragma unroll
    for (int kc = 0; kc < 4; ++kc) {
      bf16x8 af[2], bfr[4];
      #pragma unroll
      for (int i = 0; i < 2; ++i)
        af[i] = *(const bf16x8*)&As[wm + i * 16 + l16][kc * 32 + quad * 8];
      #pragma unroll
      for (int j = 0; j < 4; ++j)
        bfr[j] = *(const bf16x8*)&Bs[wn + j * 16 + l16][kc * 32 + quad * 8];
      #pragma unroll
      for (int i = 0; i < 2; ++i)
        #pragma unroll
        for (int j = 0; j < 4; ++j)
          acc[i][j] = __builtin_amdgcn_mfma_f32_16x16x32_bf16(af[i], bfr[j], acc[i][j], 0, 0, 0);
    }
    bf16u* tab = half ? pe : pr;
    #pragma unroll
    for (int j = 0; j < 4; ++j) {
      const int col = wn + j * 16 + l16;
      #pragma unroll
      for (int i = 0; i < 2; ++i) {
        #pragma unroll
        for (int r = 0; r < 4; ++r) {
          int row = row0 + wm + i * 16 + quad * 4 + r;
          if (row <= 100000) tab[(size_t)row * 128 + col] = f2b(acc[i][j][r]);
        }
      }
    }
    if (half == 0) {
      __syncthreads();
      const uint4* src = (const uint4*)(Vp + 128 * 128);
      #pragma unroll
      for (int s = 0; s < 8; ++s) {
        int f = s * 256 + t;
        *(uint4*)&Bs[f >> 4][(f & 15) * 8] = src[f];
      }
      __syncthreads();
    }
  }
}

// ---------------------------------------------------------------------------
// Merged neighbor encoder: q-left (b<4096), q-right (<8192), s-left (<8197),
// s-right (<8202). 16B gathers, LDS k-group reduce.
__global__ __launch_bounds__(256) void k_neighbor(
    const int* __restrict__ q_l1, const int* __restrict__ q_l2,
    const int* __restrict__ q_r1, const int* __restrict__ q_r2,
    const int* __restrict__ s_l1, const int* __restrict__ s_l2,
    const int* __restrict__ s_r1, const int* __restrict__ s_r2,
    const bf16u* __restrict__ pr, const bf16u* __restrict__ pe,
    const float* __restrict__ srel, const float* __restrict__ sent,
    const float* __restrict__ gcn_wb, const float* __restrict__ gcn_b,
    const float* __restrict__ hop_gate,
    float* __restrict__ qn, float* __restrict__ sn, bf16u* __restrict__ XX)
{
  const int b = blockIdx.x, t = threadIdx.x;
  const int *cA, *cB; float* outp; bf16u* xxp; int n, coloff;
  if (b < 4096)      { cA = q_l1; cB = q_l2; n = b;        outp = qn; xxp = XX; coloff = 0; }
  else if (b < 8192) { cA = q_r1; cB = q_r2; n = b - 4096; outp = qn; xxp = XX; coloff = 128; }
  else if (b < 8197) { cA = s_l1; cB = s_l2; n = b - 8192; outp = sn; xxp = 0;  coloff = 0; }
  else               { cA = s_r1; cB = s_r2; n = b - 8197; outp = sn; xxp = 0;  coloff = 128; }
  __shared__ int idxA[64][2], idxB[64][2];
  __shared__ float wA[64], wB[64];
  __shared__ float red[2][8][16][8];
  if (t < 128) {
    const int hop = t >> 6, nn = t & 63;
    const int* conn = hop ? cB : cA;
    int rel = conn[(n * 64 + nn) * 2 + 0];
    int ent = conn[(n * 64 + nn) * 2 + 1];
    int (*idx)[2] = hop ? idxB : idxA;
    idx[nn][0] = rel; idx[nn][1] = ent;
    float sc = srel[rel] + sent[ent];
    float m = sc;
    #pragma unroll
    for (int off = 32; off; off >>= 1) m = fmaxf(m, __shfl_xor(m, off, 64));
    float e = __expf(sc - m);
    float s = e;
    #pragma unroll
    for (int off = 32; off; off >>= 1) s += __shfl_xor(s, off, 64);
    (hop ? wB : wA)[nn] = e / s;
  }
  __syncthreads();
  {
    const int hop = t >> 7, g = (t >> 4) & 7, p = t & 15;
    const int (*idx)[2] = hop ? idxB : idxA;
    const float* w = hop ? wB : wA;
    float a[8];
    #pragma unroll
    for (int c = 0; c < 8; ++c) a[c] = 0.f;
    #pragma unroll
    for (int kk = 0; kk < 8; ++kk) {
      int k = g + (kk << 3);
      float wk = w[k];
      uint4 ra = *(const uint4*)&pr[(size_t)idx[k][0] * 128 + p * 8];
      uint4 rb = *(const uint4*)&pe[(size_t)idx[k][1] * 128 + p * 8];
      a[0] += wk * (blo(ra.x) + blo(rb.x)); a[1] += wk * (bhi(ra.x) + bhi(rb.x));
      a[2] += wk * (blo(ra.y) + blo(rb.y)); a[3] += wk * (bhi(ra.y) + bhi(rb.y));
      a[4] += wk * (blo(ra.z) + blo(rb.z)); a[5] += wk * (bhi(ra.z) + bhi(rb.z));
      a[6] += wk * (blo(ra.w) + blo(rb.w)); a[7] += wk * (bhi(ra.w) + bhi(rb.w));
    }
    *(float4*)&red[hop][g][p][0] = (float4){a[0], a[1], a[2], a[3]};
    *(float4*)&red[hop][g][p][4] = (float4){a[4], a[5], a[6], a[7]};
  }
  __syncthreads();
  if (t < 128) {
    const int d = t, p = d >> 3, cq = d & 7;
    float accA = 0.f, accB = 0.f;
    #pragma unroll
    for (int g = 0; g < 8; ++g) {
      accA += red[0][g][p][cq];
      accB += red[1][g][p][cq];
    }
    float bias = gcn_wb[d] + gcn_b[d];
    float g0 = hop_gate[0], g1 = hop_gate[1];
    float mx = fmaxf(g0, g1);
    float e0 = __expf(g0 - mx), e1 = __expf(g1 - mx);
    float inv = 1.f / (e0 + e1);
    float v = e0 * inv * tanhf(bias + accA) + e1 * inv * tanhf(bias + accB);
    outp[n * 256 + coloff + d] = v;
    if (xxp) xxp[(size_t)n * 576 + coloff + d] = f2b(v);
  }
}

// ---------------------------------------------------------------------------
// Support encoder stage 1: h1[r][j] = relu(sn[r] . p1_w[j] + p1_b[j]).
__global__ __launch_bounds__(256) void k_sup1(
    const float* __restrict__ sn, const float* __restrict__ p1_w,
    const float* __restrict__ p1_b, float* __restrict__ h1)
{
  const int r = blockIdx.x >> 3, j0 = (blockIdx.x & 7) << 6;
  const int t = threadIdx.x;
  __shared__ float xs[256];
  xs[t] = sn[r * 256 + t];
  __syncthreads();
  const int j = j0 + (t >> 2), q = t & 3;
  const float* wr = p1_w + (size_t)j * 256 + q * 64;
  float acc = 0.f;
  #pragma unroll
  for (int k = 0; k < 64; ++k) acc += xs[q * 64 + k] * wr[k];
  acc += __shfl_xor(acc, 1, 64);
  acc += __shfl_xor(acc, 2, 64);
  if (q == 0) h1[r * 512 + j] = fmaxf(acc + p1_b[j], 0.f);
}

// Stage 2: z = h1@p2_w.T + p2_b + sn, then LayerNorm -> sg. One block per row.
__global__ __launch_bounds__(256) void k_sup2(
    const float* __restrict__ sn, const float* __restrict__ h1,
    const float* __restrict__ p2_w, const float* __restrict__ p2_b,
    const float* __restrict__ ln_g, const float* __restrict__ ln_b,
    float* __restrict__ sg)
{
  const int r = blockIdx.x, t = threadIdx.x;
  const int lane = t & 63, wave = t >> 6;
  __shared__ float hs[512];
  __shared__ float zs[256];
  __shared__ float r1[4], r2[4];
  hs[t] = h1[r * 512 + t];
  hs[t + 256] = h1[r * 512 + 256 + t];
  __syncthreads();
  const int q = t & 3;
  #pragma unroll
  for (int jc = 0; jc < 4; ++jc) {
    int j = jc * 64 + (t >> 2);
    const float* wr = p2_w + (size_t)j * 512 + q * 128;
    float acc = 0.f;
    #pragma unroll
    for (int k = 0; k < 128; ++k) acc += hs[q * 128 + k] * wr[k];
    acc += __shfl_xor(acc, 1, 64);
    acc += __shfl_xor(acc, 2, 64);
    if (q == 0) zs[j] = acc + p2_b[j] + sn[r * 256 + j];
  }
  __syncthreads();
  float v = zs[t];
  float s1 = v, s2 = v * v;
  #pragma unroll
  for (int off = 32; off; off >>= 1) { s1 += __shfl_xor(s1, off, 64); s2 += __shfl_xor(s2, off, 64); }
  if (lane == 0) { r1[wave] = s1; r2[wave] = s2; }
  __syncthreads();
  float S1 = r1[0] + r1[1] + r1[2] + r1[3];
  float S2 = r2[0] + r2[1] + r2[2] + r2[3];
  float mu = S1 * (1.f / 256.f);
  float var = S2 * (1.f / 256.f) - mu * mu;
  sg[r * 256 + t] = (v - mu) * rsqrtf(var + 1e-6f) * ln_g[t] + ln_b[t];
}

// ---------------------------------------------------------------------------
// SG2 v2: 32 blocks x 64 j. Thread = (j, quarter). float4 loads, 2-shuffle
// reduce. Block 0 also writes sm.
__global__ __launch_bounds__(256) void k_sg2(
    const float* __restrict__ sg, const float* __restrict__ w_hh,
    bf16u* __restrict__ WWb, float* __restrict__ sm)
{
  __shared__ float s[5][256];
  const int t = threadIdx.x;
  for (int i = t; i < 1280; i += 256) s[i >> 8][i & 255] = sg[i];
  __syncthreads();
  if (blockIdx.x == 0)
    sm[t] = (s[0][t] + s[1][t] + s[2][t] + s[3][t] + s[4][t]) * 0.2f;
  const int j = (blockIdx.x << 6) + (t >> 2), q = t & 3;
  const float4* wr = (const float4*)(w_hh + (size_t)j * 512 + 256 + q * 64);
  float a[5] = {0.f, 0.f, 0.f, 0.f, 0.f};
  #pragma unroll
  for (int kk = 0; kk < 16; ++kk) {
    float4 w = wr[kk];
    int k = q * 64 + kk * 4;
    #pragma unroll
    for (int r = 0; r < 5; ++r)
      a[r] += s[r][k] * w.x + s[r][k+1] * w.y + s[r][k+2] * w.z + s[r][k+3] * w.w;
  }
  #pragma unroll
  for (int r = 0; r < 5; ++r) {
    a[r] += __shfl_xor(a[r], 1, 64);
    a[r] += __shfl_xor(a[r], 2, 64);
  }
  if (q == 0) {
    #pragma unroll
    for (int r = 0; r < 5; ++r)
      WWb[(size_t)j * 576 + 512 + r] = f2b(a[r]);
  }
}

// ---------------------------------------------------------------------------
// gates[4096][2048] (bf16) = XX[:, :K] @ WW[:, :K].T + bsum, MFMA 16x16x32.
__global__ __launch_bounds__(256) void k_gates_mfma(
    const bf16u* __restrict__ XX, const bf16u* __restrict__ WW,
    const float* __restrict__ bsum, bf16u* __restrict__ gates, int kchunks)
{
  const int t = threadIdx.x;
  const int wave = t >> 6, lane = t & 63;
  const int quad = lane >> 4, l16 = lane & 15;
  const int wm = (wave >> 1) << 6, wn = (wave & 1) << 6;
  const int row0 = (blockIdx.x >> 4) << 7;
  const int col0 = (blockIdx.x & 15) << 7;
  __shared__ short As[128][40];
  __shared__ short Bs[128][40];
  f32x4 acc[4][4];
  #pragma unroll
  for (int i = 0; i < 4; ++i)
    #pragma unroll
    for (int j = 0; j < 4; ++j) acc[i][j] = (f32x4){0.f, 0.f, 0.f, 0.f};

  const int srow = t >> 1, shalf = t & 1;
  const bf16u* xp = XX + (size_t)(row0 + srow) * 576 + shalf * 16;
  const bf16u* wp = WW + (size_t)(col0 + srow) * 576 + shalf * 16;

  uint4 x0 = *(const uint4*)(xp);
  uint4 x1 = *(const uint4*)(xp + 8);
  uint4 w0 = *(const uint4*)(wp);
  uint4 w1 = *(const uint4*)(wp + 8);

  for (int kc = 0; kc < kchunks; ++kc) {
    __syncthreads();
    *(uint4*)&As[srow][shalf * 16] = x0;
    *(uint4*)&As[srow][shalf * 16 + 8] = x1;
    *(uint4*)&Bs[srow][shalf * 16] = w0;
    *(uint4*)&Bs[srow][shalf * 16 + 8] = w1;
    __syncthreads();
    if (kc + 1 < kchunks) {
      x0 = *(const uint4*)(xp + (kc+1) * 32);
      x1 = *(const uint4*)(xp + (kc+1) * 32 + 8);
      w0 = *(const uint4*)(wp + (kc+1) * 32);
      w1 = *(const uint4*)(wp + (kc+1) * 32 + 8);
    }
    bf16x8 af[4], bfr[4];
    #pragma unroll
    for (int i = 0; i < 4; ++i)
      af[i] = *(const bf16x8*)&As[wm + i * 16 + l16][quad * 8];
    #pragma unroll
    for (int j = 0; j < 4; ++j)
      bfr[j] = *(const bf16x8*)&Bs[wn + j * 16 + l16][quad * 8];
    #pragma unroll
    for (int i = 0; i < 4; ++i)
      #pragma unroll
      for (int j = 0; j < 4; ++j)
        acc[i][j] = __builtin_amdgcn_mfma_f32_16x16x32_bf16(af[i], bfr[j], acc[i][j], 0, 0, 0);
  }

  #pragma unroll
  for (int j = 0; j < 4; ++j) {
    const int col = col0 + wn + j * 16 + l16;
    const float bs = bsum[col];
    #pragma unroll
    for (int i = 0; i < 4; ++i) {
      #pragma unroll
      for (int r = 0; r < 4; ++r) {
        int row = row0 + wm + i * 16 + quad * 4 + r;
        gates[(size_t)row * 2048 + col] = f2b(acc[i][j][r] + bs);
      }
    }
  }
}

// ---------------------------------------------------------------------------
__device__ inline float block_sum256(float v, float* red) {
  const int lane = threadIdx.x & 63, wave = threadIdx.x >> 6;
  #pragma unroll
  for (int off = 32; off; off >>= 1) v += __shfl_xor(v, off, 64);
  if (lane == 0) red[wave] = v;
  __syncthreads();
  float r = red[0] + red[1] + red[2] + red[3];
  __syncthreads();
  return r;
}

// Cell pointwise + attention (writes bf16 hc/attn into XX) or final output.
__global__ __launch_bounds__(256) void k_cell(
    const bf16u* __restrict__ gates, const float* __restrict__ qn,
    float* __restrict__ c, bf16u* __restrict__ XX,
    const float* __restrict__ sg, const float* __restrict__ sm,
    float* __restrict__ out, int step)
{
  __shared__ float red[4];
  const int b = blockIdx.x, t = threadIdx.x;
  const bf16u* g = gates + (size_t)b * 2048;
  float i0 = b2f(g[t]),       f0 = b2f(g[512 + t]), gg0 = b2f(g[1024 + t]), o0 = b2f(g[1536 + t]);
  float i1 = b2f(g[256 + t]), f1 = b2f(g[768 + t]), gg1 = b2f(g[1280 + t]);
  float co0 = step ? c[b * 512 + t] : 0.f;
  float co1 = step ? c[b * 512 + 256 + t] : 0.f;
  float c0 = sigmoidf_(f0) * co0 + sigmoidf_(i0) * tanhf(gg0);
  float c1 = sigmoidf_(f1) * co1 + sigmoidf_(i1) * tanhf(gg1);
  c[b * 512 + t] = c0;
  c[b * 512 + 256 + t] = c1;
  float hcv = sigmoidf_(o0) * tanhf(c0);
  float h = qn[b * 256 + t] + hcv;
  if (step < 3) {
    XX[(size_t)b * 576 + 256 + t] = f2b(hcv);
    float dots[5];
    #pragma unroll
    for (int s = 0; s < 5; ++s) dots[s] = block_sum256(h * sg[s * 256 + t], red);
    float m = dots[0];
    #pragma unroll
    for (int s = 1; s < 5; ++s) m = fmaxf(m, dots[s]);
    float sum = 0.f;
    #pragma unroll
    for (int s = 0; s < 5; ++s) sum += __expf(dots[s] - m);
    if (t < 5) {
      float dv = (t == 1) ? dots[1] : (t == 2) ? dots[2] : (t == 3) ? dots[3]
               : (t == 4) ? dots[4] : dots[0];
      XX[(size_t)b * 576 + 512 + t] = f2b(__expf(dv - m) / sum);
    }
  } else {
    float tot = block_sum256(h * sm[t], red);
    if (t == 0) out[b] = tot;
  }
}

// ---------------------------------------------------------------------------
extern "C" void kernel_launch(void* const* d_in, const int* in_sizes, int n_in,
                              void* d_out, int out_size, void* d_ws, size_t ws_size,
                              hipStream_t stream)
{
  (void)in_sizes; (void)n_in; (void)out_size; (void)ws_size;
  const int *q_l1 = (const int*)d_in[0], *q_l2 = (const int*)d_in[1];
  const int *q_r1 = (const int*)d_in[2], *q_r2 = (const int*)d_in[3];
  const int *s_l1 = (const int*)d_in[4], *s_l2 = (const int*)d_in[5];
  const int *s_r1 = (const int*)d_in[6], *s_r2 = (const int*)d_in[7];
  const float* emb      = (const float*)d_in[12];
  const float* gcn_w    = (const float*)d_in[13];
  const float* gcn_wb   = (const float*)d_in[14];
  const float* gcn_b    = (const float*)d_in[15];
  const float* hop_gate = (const float*)d_in[16];
  const float* attn_w   = (const float*)d_in[17];
  const float* p1_w = (const float*)d_in[19];
  const float* p1_b = (const float*)d_in[20];
  const float* p2_w = (const float*)d_in[21];
  const float* p2_b = (const float*)d_in[22];
  const float* ln_g = (const float*)d_in[23];
  const float* ln_b = (const float*)d_in[24];
  const float* w_ih = (const float*)d_in[25];
  const float* w_hh = (const float*)d_in[26];
  const float* b_ih = (const float*)d_in[27];
  const float* b_hh = (const float*)d_in[28];

  char* base = (char*)d_ws;
  size_t off = 0;
  auto alloc = [&](size_t bytes) -> char* {
    char* r = base + off;
    off = (off + bytes + 255) & ~(size_t)255;
    return r;
  };
  bf16u* pr    = (bf16u*)alloc(100001ull * 128 * 2);
  bf16u* pe    = (bf16u*)alloc(100001ull * 128 * 2);
  float* srel  = (float*)alloc(100001ull * 4);
  float* sent  = (float*)alloc(100001ull * 4);
  float* uvec  = (float*)alloc(256 * 4);
  bf16u* Vp    = (bf16u*)alloc(256 * 128 * 2);
  float* qn    = (float*)alloc(4096ull * 256 * 4);
  float* sn    = (float*)alloc(5 * 256 * 4);
  float* sg    = (float*)alloc(5 * 256 * 4);
  float* sm    = (float*)alloc(256 * 4);
  float* h1b   = (float*)alloc(5 * 512 * 4);
  bf16u* XX    = (bf16u*)alloc(4096ull * 576 * 2);
  bf16u* WWa   = (bf16u*)alloc(2048ull * 576 * 2);
  bf16u* WWb   = (bf16u*)alloc(2048ull * 576 * 2);
  float* bsum  = (float*)alloc(2048 * 4);
  bf16u* gates = (bf16u*)alloc(4096ull * 2048 * 2);
  float* cbuf  = (float*)alloc(4096ull * 512 * 4);

  k_prep<<<4096, 256, 0, stream>>>(gcn_w, attn_w, w_ih, w_hh, b_ih, b_hh,
                                   Vp, uvec, WWa, WWb, bsum, XX);
  k_pre_gemm<<<1563, 256, 0, stream>>>(emb, Vp, uvec, pr, pe, srel, sent);
  k_neighbor<<<8202, 256, 0, stream>>>(q_l1, q_l2, q_r1, q_r2, s_l1, s_l2, s_r1, s_r2,
                                       pr, pe, srel, sent, gcn_wb, gcn_b, hop_gate,
                                       qn, sn, XX);
  k_sup1<<<40, 256, 0, stream>>>(sn, p1_w, p1_b, h1b);
  k_sup2<<<5, 256, 0, stream>>>(sn, h1b, p2_w, p2_b, ln_g, ln_b, sg);
  k_sg2<<<32, 256, 0, stream>>>(sg, w_hh, WWb, sm);

  for (int step = 0; step < 4; ++step) {
    if (step == 0)
      k_gates_mfma<<<512, 256, 0, stream>>>(XX, WWa, bsum, gates, 8);
    else
      k_gates_mfma<<<512, 256, 0, stream>>>(XX, WWb, bsum, gates, 17);
    k_cell<<<4096, 256, 0, stream>>>(gates, qn, cbuf, XX, sg, sm, (float*)d_out, step);
  }
}

// Round 10
// 343.478 us; speedup vs baseline: 4.8264x; 1.1537x over previous
//
#include <hip/hip_runtime.h>

typedef unsigned short bf16u;
typedef unsigned char u8;
typedef unsigned int u32;
typedef float f32x4 __attribute__((ext_vector_type(4)));
typedef short bf16x8 __attribute__((ext_vector_type(8)));

__device__ inline float sigmoidf_(float x) { return 1.f / (1.f + __expf(-x)); }
__device__ inline float b2f(bf16u u) { return __uint_as_float(((u32)u) << 16); }
__device__ inline bf16u f2b(float f) {
  u32 i = __float_as_uint(f);
  u32 r = (i + 0x7fffu + ((i >> 16) & 1u)) >> 16;
  return (bf16u)r;
}
// uint8 table codec: stored = clamp(round(v*512 + 128)); decoded = u/512 - 0.25
__device__ inline u8 enc8(float v) {
  float q = fmaf(v, 512.f, 128.5f);
  q = fminf(fmaxf(q, 0.f), 255.f);
  return (u8)(int)q;
}
// byte i of word -> float; compiles to v_cvt_f32_ubyte{0..3}
__device__ inline float ub0(u32 u) { return (float)(u & 0xffu); }
__device__ inline float ub1(u32 u) { return (float)((u >> 8) & 0xffu); }
__device__ inline float ub2(u32 u) { return (float)((u >> 16) & 0xffu); }
__device__ inline float ub3(u32 u) { return (float)(u >> 24); }

// ---------------------------------------------------------------------------
// Fused prep: XX pad zero (all 4096 blocks), LSTM weight pack (b<2048),
// Vp bf16 conversion (b in [2048,2304)), uvec (b==2304).
__global__ __launch_bounds__(256) void k_prep(
    const float* __restrict__ gcn_w, const float* __restrict__ attn_w,
    const float* __restrict__ w_ih, const float* __restrict__ w_hh,
    const float* __restrict__ b_ih, const float* __restrict__ b_hh,
    bf16u* __restrict__ Vp, float* __restrict__ uvec,
    bf16u* __restrict__ WWa, bf16u* __restrict__ WWb, float* __restrict__ bsum,
    bf16u* __restrict__ XX)
{
  const int b = blockIdx.x, t = threadIdx.x;
  if (t < 27) XX[(size_t)b * 576 + 517 + t] = 0;
  if (b < 2048) {
    float wi = w_ih[b * 256 + t];
    float wh = w_hh[b * 512 + t];
    WWa[(size_t)b * 576 + t] = f2b(wi);
    WWb[(size_t)b * 576 + t] = f2b(wi + wh);
    WWb[(size_t)b * 576 + 256 + t] = f2b(wh);
    if (t < 27) WWb[(size_t)b * 576 + 517 + t] = 0;
    if (t == 0) bsum[b] = b_ih[b] + b_hh[b];
  } else if (b < 2304) {
    const int o = b - 2048;
    if (t < 128) Vp[o * 128 + t] = f2b(gcn_w[(o & 127) * 256 + ((o >> 7) << 7) + t]);
  } else if (b == 2304) {
    const int col = ((t >> 7) << 7) + (t & 127);
    float acc = 0.f;
    for (int d = 0; d < 128; ++d) acc += gcn_w[d * 256 + col] * attn_w[d];
    uvec[t] = acc;
  }
}

// ---------------------------------------------------------------------------
// pr/pe tables (uint8) via bf16 MFMA; scores computed post-staging from LDS.
__global__ __launch_bounds__(256) void k_pre_gemm(
    const float* __restrict__ emb, const bf16u* __restrict__ Vp,
    const float* __restrict__ uvec,
    u8* __restrict__ pr, u8* __restrict__ pe,
    float* __restrict__ srel, float* __restrict__ sent)
{
  const int t = threadIdx.x;
  const int row0 = blockIdx.x << 6;
  __shared__ short As[64][136];
  __shared__ short Bs[128][136];
  __shared__ float us[256];
  us[t] = uvec[t];
  {
    const uint4* src = (const uint4*)Vp;
    #pragma unroll
    for (int s = 0; s < 8; ++s) {
      int f = s * 256 + t;
      *(uint4*)&Bs[f >> 4][(f & 15) * 8] = src[f];
    }
  }
  // stage A (fp32 -> bf16), pure streaming
  #pragma unroll
  for (int s = 0; s < 8; ++s) {
    int f = s * 256 + t;
    int row = f >> 5, q = f & 31;
    int gr = row0 + row; if (gr > 100000) gr = 100000;
    float4 v = *(const float4*)&emb[(size_t)gr * 128 + (q << 2)];
    ushort4 pk;
    pk.x = f2b(v.x); pk.y = f2b(v.y); pk.z = f2b(v.z); pk.w = f2b(v.w);
    *(ushort4*)&As[row][q << 2] = pk;
  }
  __syncthreads();
  // fused scores from staged bf16 A: 4 lanes per row
  {
    const int row = t >> 2, l = t & 3;
    int gr = row0 + row; if (gr > 100000) gr = 100000;
    const short* ar = &As[row][l * 32];
    const float* u0 = &us[l * 32];
    const float* u1 = &us[128 + l * 32];
    float p0 = 0.f, p1 = 0.f;
    #pragma unroll
    for (int i = 0; i < 32; ++i) {
      float e = __uint_as_float(((u32)(unsigned short)ar[i]) << 16);
      p0 += e * u0[i];
      p1 += e * u1[i];
    }
    p0 += __shfl_xor(p0, 1, 64); p0 += __shfl_xor(p0, 2, 64);
    p1 += __shfl_xor(p1, 1, 64); p1 += __shfl_xor(p1, 2, 64);
    if (l == 0) { srel[gr] = p0; sent[gr] = p1; }
  }
  const int wave = t >> 6, lane = t & 63;
  const int quad = lane >> 4, l16 = lane & 15;
  const int wm = (wave >> 1) << 5, wn = (wave & 1) << 6;
  #pragma unroll
  for (int half = 0; half < 2; ++half) {
    f32x4 acc[2][4];
    #pragma unroll
    for (int i = 0; i < 2; ++i)
      #pragma unroll
      for (int j = 0; j < 4; ++j) acc[i][j] = (f32x4){0.f, 0.f, 0.f, 0.f};
    #pragma unroll
    for (int kc = 0; kc < 4; ++kc) {
      bf16x8 af[2], bfr[4];
      #pragma unroll
      for (int i = 0; i < 2; ++i)
        af[i] = *(const bf16x8*)&As[wm + i * 16 + l16][kc * 32 + quad * 8];
      #pragma unroll
      for (int j = 0; j < 4; ++j)   // Bs holds the current half's 128 cols
        bfr[j] = *(const bf16x8*)&Bs[wn + j * 16 + l16][kc * 32 + quad * 8];
      #pragma unroll
      for (int i = 0; i < 2; ++i)
        #pragma unroll
        for (int j = 0; j < 4; ++j)
          acc[i][j] = __builtin_amdgcn_mfma_f32_16x16x32_bf16(af[i], bfr[j], acc[i][j], 0, 0, 0);
    }
    u8* tab = half ? pe : pr;
    #pragma unroll
    for (int j = 0; j < 4; ++j) {
      const int col = wn + j * 16 + l16;
      #pragma unroll
      for (int i = 0; i < 2; ++i) {
        #pragma unroll
        for (int r = 0; r < 4; ++r) {
          int row = row0 + wm + i * 16 + quad * 4 + r;
          if (row <= 100000) tab[(size_t)row * 128 + col] = enc8(acc[i][j][r]);
        }
      }
    }
    if (half == 0) {
      __syncthreads();
      const uint4* src = (const uint4*)(Vp + 128 * 128);
      #pragma unroll
      for (int s = 0; s < 8; ++s) {
        int f = s * 256 + t;
        *(uint4*)&Bs[f >> 4][(f & 15) * 8] = src[f];
      }
      __syncthreads();
    }
  }
}

// ---------------------------------------------------------------------------
// Merged neighbor encoder with uint8 tables: q-left (b<4096), q-right (<8192),
// s-left (<8197), s-right (<8202). uint2 gathers + register prefetch.
__global__ __launch_bounds__(256) void k_neighbor(
    const int* __restrict__ q_l1, const int* __restrict__ q_l2,
    const int* __restrict__ q_r1, const int* __restrict__ q_r2,
    const int* __restrict__ s_l1, const int* __restrict__ s_l2,
    const int* __restrict__ s_r1, const int* __restrict__ s_r2,
    const u8* __restrict__ pr, const u8* __restrict__ pe,
    const float* __restrict__ srel, const float* __restrict__ sent,
    const float* __restrict__ gcn_wb, const float* __restrict__ gcn_b,
    const float* __restrict__ hop_gate,
    float* __restrict__ qn, float* __restrict__ sn, bf16u* __restrict__ XX)
{
  const int b = blockIdx.x, t = threadIdx.x;
  const int *cA, *cB; float* outp; bf16u* xxp; int n, coloff;
  if (b < 4096)      { cA = q_l1; cB = q_l2; n = b;        outp = qn; xxp = XX; coloff = 0; }
  else if (b < 8192) { cA = q_r1; cB = q_r2; n = b - 4096; outp = qn; xxp = XX; coloff = 128; }
  else if (b < 8197) { cA = s_l1; cB = s_l2; n = b - 8192; outp = sn; xxp = 0;  coloff = 0; }
  else               { cA = s_r1; cB = s_r2; n = b - 8197; outp = sn; xxp = 0;  coloff = 128; }
  __shared__ int idxA[64][2], idxB[64][2];
  __shared__ float wA[64], wB[64];
  __shared__ float red[2][8][16][8];
  if (t < 128) {
    const int hop = t >> 6, nn = t & 63;
    const int* conn = hop ? cB : cA;
    int rel = conn[(n * 64 + nn) * 2 + 0];
    int ent = conn[(n * 64 + nn) * 2 + 1];
    int (*idx)[2] = hop ? idxB : idxA;
    idx[nn][0] = rel; idx[nn][1] = ent;
    float sc = srel[rel] + sent[ent];
    float m = sc;
    #pragma unroll
    for (int off = 32; off; off >>= 1) m = fmaxf(m, __shfl_xor(m, off, 64));
    float e = __expf(sc - m);
    float s = e;
    #pragma unroll
    for (int off = 32; off; off >>= 1) s += __shfl_xor(s, off, 64);
    (hop ? wB : wA)[nn] = e / s;
  }
  __syncthreads();
  {
    const int hop = t >> 7, g = (t >> 4) & 7, p = t & 15;
    const int (*idx)[2] = hop ? idxB : idxA;
    const float* w = hop ? wB : wA;
    uint2 ra[8], rb[8];
    #pragma unroll
    for (int kk = 0; kk < 8; ++kk) {
      int k = g + (kk << 3);
      ra[kk] = *(const uint2*)&pr[(size_t)idx[k][0] * 128 + p * 8];
      rb[kk] = *(const uint2*)&pe[(size_t)idx[k][1] * 128 + p * 8];
    }
    float a[8];
    #pragma unroll
    for (int c = 0; c < 8; ++c) a[c] = 0.f;
    #pragma unroll
    for (int kk = 0; kk < 8; ++kk) {
      float wk = w[g + (kk << 3)];
      a[0] += wk * (ub0(ra[kk].x) + ub0(rb[kk].x));
      a[1] += wk * (ub1(ra[kk].x) + ub1(rb[kk].x));
      a[2] += wk * (ub2(ra[kk].x) + ub2(rb[kk].x));
      a[3] += wk * (ub3(ra[kk].x) + ub3(rb[kk].x));
      a[4] += wk * (ub0(ra[kk].y) + ub0(rb[kk].y));
      a[5] += wk * (ub1(ra[kk].y) + ub1(rb[kk].y));
      a[6] += wk * (ub2(ra[kk].y) + ub2(rb[kk].y));
      a[7] += wk * (ub3(ra[kk].y) + ub3(rb[kk].y));
    }
    *(float4*)&red[hop][g][p][0] = (float4){a[0], a[1], a[2], a[3]};
    *(float4*)&red[hop][g][p][4] = (float4){a[4], a[5], a[6], a[7]};
  }
  __syncthreads();
  if (t < 128) {
    const int d = t, p = d >> 3, cq = d & 7;
    float sA = 0.f, sB = 0.f;
    #pragma unroll
    for (int g = 0; g < 8; ++g) {
      sA += red[0][g][p][cq];
      sB += red[1][g][p][cq];
    }
    // decode: tables hold u = v*512+128 per element; Σw = 1 per hop
    float accA = sA * (1.f / 512.f) - 0.5f;
    float accB = sB * (1.f / 512.f) - 0.5f;
    float bias = gcn_wb[d] + gcn_b[d];
    float g0 = hop_gate[0], g1 = hop_gate[1];
    float mx = fmaxf(g0, g1);
    float e0 = __expf(g0 - mx), e1 = __expf(g1 - mx);
    float inv = 1.f / (e0 + e1);
    float v = e0 * inv * tanhf(bias + accA) + e1 * inv * tanhf(bias + accB);
    outp[n * 256 + coloff + d] = v;
    if (xxp) xxp[(size_t)n * 576 + coloff + d] = f2b(v);
  }
}

// ---------------------------------------------------------------------------
// Support encoder stage 1: h1[r][j] = relu(sn[r] . p1_w[j] + p1_b[j]).
__global__ __launch_bounds__(256) void k_sup1(
    const float* __restrict__ sn, const float* __restrict__ p1_w,
    const float* __restrict__ p1_b, float* __restrict__ h1)
{
  const int r = blockIdx.x >> 3, j0 = (blockIdx.x & 7) << 6;
  const int t = threadIdx.x;
  __shared__ float xs[256];
  xs[t] = sn[r * 256 + t];
  __syncthreads();
  const int j = j0 + (t >> 2), q = t & 3;
  const float* wr = p1_w + (size_t)j * 256 + q * 64;
  float acc = 0.f;
  #pragma unroll
  for (int k = 0; k < 64; ++k) acc += xs[q * 64 + k] * wr[k];
  acc += __shfl_xor(acc, 1, 64);
  acc += __shfl_xor(acc, 2, 64);
  if (q == 0) h1[r * 512 + j] = fmaxf(acc + p1_b[j], 0.f);
}

// Stage 2: z = h1@p2_w.T + p2_b + sn, then LayerNorm -> sg. One block per row.
__global__ __launch_bounds__(256) void k_sup2(
    const float* __restrict__ sn, const float* __restrict__ h1,
    const float* __restrict__ p2_w, const float* __restrict__ p2_b,
    const float* __restrict__ ln_g, const float* __restrict__ ln_b,
    float* __restrict__ sg)
{
  const int r = blockIdx.x, t = threadIdx.x;
  const int lane = t & 63, wave = t >> 6;
  __shared__ float hs[512];
  __shared__ float zs[256];
  __shared__ float r1[4], r2[4];
  hs[t] = h1[r * 512 + t];
  hs[t + 256] = h1[r * 512 + 256 + t];
  __syncthreads();
  const int q = t & 3;
  #pragma unroll
  for (int jc = 0; jc < 4; ++jc) {
    int j = jc * 64 + (t >> 2);
    const float* wr = p2_w + (size_t)j * 512 + q * 128;
    float acc = 0.f;
    #pragma unroll
    for (int k = 0; k < 128; ++k) acc += hs[q * 128 + k] * wr[k];
    acc += __shfl_xor(acc, 1, 64);
    acc += __shfl_xor(acc, 2, 64);
    if (q == 0) zs[j] = acc + p2_b[j] + sn[r * 256 + j];
  }
  __syncthreads();
  float v = zs[t];
  float s1 = v, s2 = v * v;
  #pragma unroll
  for (int off = 32; off; off >>= 1) { s1 += __shfl_xor(s1, off, 64); s2 += __shfl_xor(s2, off, 64); }
  if (lane == 0) { r1[wave] = s1; r2[wave] = s2; }
  __syncthreads();
  float S1 = r1[0] + r1[1] + r1[2] + r1[3];
  float S2 = r2[0] + r2[1] + r2[2] + r2[3];
  float mu = S1 * (1.f / 256.f);
  float var = S2 * (1.f / 256.f) - mu * mu;
  sg[r * 256 + t] = (v - mu) * rsqrtf(var + 1e-6f) * ln_g[t] + ln_b[t];
}

// ---------------------------------------------------------------------------
// SG2 v2: 32 blocks x 64 j. Thread = (j, quarter). float4 loads, 2-shuffle
// reduce. Block 0 also writes sm.
__global__ __launch_bounds__(256) void k_sg2(
    const float* __restrict__ sg, const float* __restrict__ w_hh,
    bf16u* __restrict__ WWb, float* __restrict__ sm)
{
  __shared__ float s[5][256];
  const int t = threadIdx.x;
  for (int i = t; i < 1280; i += 256) s[i >> 8][i & 255] = sg[i];
  __syncthreads();
  if (blockIdx.x == 0)
    sm[t] = (s[0][t] + s[1][t] + s[2][t] + s[3][t] + s[4][t]) * 0.2f;
  const int j = (blockIdx.x << 6) + (t >> 2), q = t & 3;
  const float4* wr = (const float4*)(w_hh + (size_t)j * 512 + 256 + q * 64);
  float a[5] = {0.f, 0.f, 0.f, 0.f, 0.f};
  #pragma unroll
  for (int kk = 0; kk < 16; ++kk) {
    float4 w = wr[kk];
    int k = q * 64 + kk * 4;
    #pragma unroll
    for (int r = 0; r < 5; ++r)
      a[r] += s[r][k] * w.x + s[r][k+1] * w.y + s[r][k+2] * w.z + s[r][k+3] * w.w;
  }
  #pragma unroll
  for (int r = 0; r < 5; ++r) {
    a[r] += __shfl_xor(a[r], 1, 64);
    a[r] += __shfl_xor(a[r], 2, 64);
  }
  if (q == 0) {
    #pragma unroll
    for (int r = 0; r < 5; ++r)
      WWb[(size_t)j * 576 + 512 + r] = f2b(a[r]);
  }
}

// ---------------------------------------------------------------------------
// gates[4096][2048] (bf16) = XX[:, :K] @ WW[:, :K].T + bsum, MFMA 16x16x32.
__global__ __launch_bounds__(256) void k_gates_mfma(
    const bf16u* __restrict__ XX, const bf16u* __restrict__ WW,
    const float* __restrict__ bsum, bf16u* __restrict__ gates, int kchunks)
{
  const int t = threadIdx.x;
  const int wave = t >> 6, lane = t & 63;
  const int quad = lane >> 4, l16 = lane & 15;
  const int wm = (wave >> 1) << 6, wn = (wave & 1) << 6;
  const int row0 = (blockIdx.x >> 4) << 7;
  const int col0 = (blockIdx.x & 15) << 7;
  __shared__ short As[128][40];
  __shared__ short Bs[128][40];
  f32x4 acc[4][4];
  #pragma unroll
  for (int i = 0; i < 4; ++i)
    #pragma unroll
    for (int j = 0; j < 4; ++j) acc[i][j] = (f32x4){0.f, 0.f, 0.f, 0.f};

  const int srow = t >> 1, shalf = t & 1;
  const bf16u* xp = XX + (size_t)(row0 + srow) * 576 + shalf * 16;
  const bf16u* wp = WW + (size_t)(col0 + srow) * 576 + shalf * 16;

  uint4 x0 = *(const uint4*)(xp);
  uint4 x1 = *(const uint4*)(xp + 8);
  uint4 w0 = *(const uint4*)(wp);
  uint4 w1 = *(const uint4*)(wp + 8);

  for (int kc = 0; kc < kchunks; ++kc) {
    __syncthreads();
    *(uint4*)&As[srow][shalf * 16] = x0;
    *(uint4*)&As[srow][shalf * 16 + 8] = x1;
    *(uint4*)&Bs[srow][shalf * 16] = w0;
    *(uint4*)&Bs[srow][shalf * 16 + 8] = w1;
    __syncthreads();
    if (kc + 1 < kchunks) {
      x0 = *(const uint4*)(xp + (kc+1) * 32);
      x1 = *(const uint4*)(xp + (kc+1) * 32 + 8);
      w0 = *(const uint4*)(wp + (kc+1) * 32);
      w1 = *(const uint4*)(wp + (kc+1) * 32 + 8);
    }
    bf16x8 af[4], bfr[4];
    #pragma unroll
    for (int i = 0; i < 4; ++i)
      af[i] = *(const bf16x8*)&As[wm + i * 16 + l16][quad * 8];
    #pragma unroll
    for (int j = 0; j < 4; ++j)
      bfr[j] = *(const bf16x8*)&Bs[wn + j * 16 + l16][quad * 8];
    #pragma unroll
    for (int i = 0; i < 4; ++i)
      #pragma unroll
      for (int j = 0; j < 4; ++j)
        acc[i][j] = __builtin_amdgcn_mfma_f32_16x16x32_bf16(af[i], bfr[j], acc[i][j], 0, 0, 0);
  }

  #pragma unroll
  for (int j = 0; j < 4; ++j) {
    const int col = col0 + wn + j * 16 + l16;
    const float bs = bsum[col];
    #pragma unroll
    for (int i = 0; i < 4; ++i) {
      #pragma unroll
      for (int r = 0; r < 4; ++r) {
        int row = row0 + wm + i * 16 + quad * 4 + r;
        gates[(size_t)row * 2048 + col] = f2b(acc[i][j][r] + bs);
      }
    }
  }
}

// ---------------------------------------------------------------------------
__device__ inline float block_sum256(float v, float* red) {
  const int lane = threadIdx.x & 63, wave = threadIdx.x >> 6;
  #pragma unroll
  for (int off = 32; off; off >>= 1) v += __shfl_xor(v, off, 64);
  if (lane == 0) red[wave] = v;
  __syncthreads();
  float r = red[0] + red[1] + red[2] + red[3];
  __syncthreads();
  return r;
}

// Cell pointwise + attention (writes bf16 hc/attn into XX) or final output.
__global__ __launch_bounds__(256) void k_cell(
    const bf16u* __restrict__ gates, const float* __restrict__ qn,
    float* __restrict__ c, bf16u* __restrict__ XX,
    const float* __restrict__ sg, const float* __restrict__ sm,
    float* __restrict__ out, int step)
{
  __shared__ float red[4];
  const int b = blockIdx.x, t = threadIdx.x;
  const bf16u* g = gates + (size_t)b * 2048;
  float i0 = b2f(g[t]),       f0 = b2f(g[512 + t]), gg0 = b2f(g[1024 + t]), o0 = b2f(g[1536 + t]);
  float i1 = b2f(g[256 + t]), f1 = b2f(g[768 + t]), gg1 = b2f(g[1280 + t]);
  float co0 = step ? c[b * 512 + t] : 0.f;
  float co1 = step ? c[b * 512 + 256 + t] : 0.f;
  float c0 = sigmoidf_(f0) * co0 + sigmoidf_(i0) * tanhf(gg0);
  float c1 = sigmoidf_(f1) * co1 + sigmoidf_(i1) * tanhf(gg1);
  c[b * 512 + t] = c0;
  c[b * 512 + 256 + t] = c1;
  float hcv = sigmoidf_(o0) * tanhf(c0);
  float h = qn[b * 256 + t] + hcv;
  if (step < 3) {
    XX[(size_t)b * 576 + 256 + t] = f2b(hcv);
    float dots[5];
    #pragma unroll
    for (int s = 0; s < 5; ++s) dots[s] = block_sum256(h * sg[s * 256 + t], red);
    float m = dots[0];
    #pragma unroll
    for (int s = 1; s < 5; ++s) m = fmaxf(m, dots[s]);
    float sum = 0.f;
    #pragma unroll
    for (int s = 0; s < 5; ++s) sum += __expf(dots[s] - m);
    if (t < 5) {
      float dv = (t == 1) ? dots[1] : (t == 2) ? dots[2] : (t == 3) ? dots[3]
               : (t == 4) ? dots[4] : dots[0];
      XX[(size_t)b * 576 + 512 + t] = f2b(__expf(dv - m) / sum);
    }
  } else {
    float tot = block_sum256(h * sm[t], red);
    if (t == 0) out[b] = tot;
  }
}

// ---------------------------------------------------------------------------
extern "C" void kernel_launch(void* const* d_in, const int* in_sizes, int n_in,
                              void* d_out, int out_size, void* d_ws, size_t ws_size,
                              hipStream_t stream)
{
  (void)in_sizes; (void)n_in; (void)out_size; (void)ws_size;
  const int *q_l1 = (const int*)d_in[0], *q_l2 = (const int*)d_in[1];
  const int *q_r1 = (const int*)d_in[2], *q_r2 = (const int*)d_in[3];
  const int *s_l1 = (const int*)d_in[4], *s_l2 = (const int*)d_in[5];
  const int *s_r1 = (const int*)d_in[6], *s_r2 = (const int*)d_in[7];
  const float* emb      = (const float*)d_in[12];
  const float* gcn_w    = (const float*)d_in[13];
  const float* gcn_wb   = (const float*)d_in[14];
  const float* gcn_b    = (const float*)d_in[15];
  const float* hop_gate = (const float*)d_in[16];
  const float* attn_w   = (const float*)d_in[17];
  const float* p1_w = (const float*)d_in[19];
  const float* p1_b = (const float*)d_in[20];
  const float* p2_w = (const float*)d_in[21];
  const float* p2_b = (const float*)d_in[22];
  const float* ln_g = (const float*)d_in[23];
  const float* ln_b = (const float*)d_in[24];
  const float* w_ih = (const float*)d_in[25];
  const float* w_hh = (const float*)d_in[26];
  const float* b_ih = (const float*)d_in[27];
  const float* b_hh = (const float*)d_in[28];

  char* base = (char*)d_ws;
  size_t off = 0;
  auto alloc = [&](size_t bytes) -> char* {
    char* r = base + off;
    off = (off + bytes + 255) & ~(size_t)255;
    return r;
  };
  u8* pr       = (u8*)alloc(100001ull * 128);
  u8* pe       = (u8*)alloc(100001ull * 128);
  float* srel  = (float*)alloc(100001ull * 4);
  float* sent  = (float*)alloc(100001ull * 4);
  float* uvec  = (float*)alloc(256 * 4);
  bf16u* Vp    = (bf16u*)alloc(256 * 128 * 2);
  float* qn    = (float*)alloc(4096ull * 256 * 4);
  float* sn    = (float*)alloc(5 * 256 * 4);
  float* sg    = (float*)alloc(5 * 256 * 4);
  float* sm    = (float*)alloc(256 * 4);
  float* h1b   = (float*)alloc(5 * 512 * 4);
  bf16u* XX    = (bf16u*)alloc(4096ull * 576 * 2);
  bf16u* WWa   = (bf16u*)alloc(2048ull * 576 * 2);
  bf16u* WWb   = (bf16u*)alloc(2048ull * 576 * 2);
  float* bsum  = (float*)alloc(2048 * 4);
  bf16u* gates = (bf16u*)alloc(4096ull * 2048 * 2);
  float* cbuf  = (float*)alloc(4096ull * 512 * 4);

  k_prep<<<4096, 256, 0, stream>>>(gcn_w, attn_w, w_ih, w_hh, b_ih, b_hh,
                                   Vp, uvec, WWa, WWb, bsum, XX);
  k_pre_gemm<<<1563, 256, 0, stream>>>(emb, Vp, uvec, pr, pe, srel, sent);
  k_neighbor<<<8202, 256, 0, stream>>>(q_l1, q_l2, q_r1, q_r2, s_l1, s_l2, s_r1, s_r2,
                                       pr, pe, srel, sent, gcn_wb, gcn_b, hop_gate,
                                       qn, sn, XX);
  k_sup1<<<40, 256, 0, stream>>>(sn, p1_w, p1_b, h1b);
  k_sup2<<<5, 256, 0, stream>>>(sn, h1b, p2_w, p2_b, ln_g, ln_b, sg);
  k_sg2<<<32, 256, 0, stream>>>(sg, w_hh, WWb, sm);

  for (int step = 0; step < 4; ++step) {
    if (step == 0)
      k_gates_mfma<<<512, 256, 0, stream>>>(XX, WWa, bsum, gates, 8);
    else
      k_gates_mfma<<<512, 256, 0, stream>>>(XX, WWb, bsum, gates, 17);
    k_cell<<<4096, 256, 0, stream>>>(gates, qn, cbuf, XX, sg, sm, (float*)d_out, step);
  }
}